// Round 3
// baseline (1574.523 us; speedup 1.0000x reference)
//
#include <hip/hip_runtime.h>
#include <hip/hip_bf16.h>
#include <cstdint>
#include <cstddef>

// ---------------- problem constants ----------------
#define HDIM    64
#define WDIM    64
#define LPB     4096            // tokens per batch
#define DMODEL  512
#define DIN     1024
#define CONVD   1088
#define DPROJ   2240            // 2*DIN + 2*32 + 128
#define NHEADS  128

using bf16   = __bf16;
using bf16x8 = __attribute__((ext_vector_type(8))) __bf16;
using bf16x4 = __attribute__((ext_vector_type(4))) __bf16;
using f32x4  = __attribute__((ext_vector_type(4))) float;

__device__ __forceinline__ float siluf(float x) { return x / (1.f + __expf(-x)); }

// ---------------- hi/lo split prep ----------------
__global__ __launch_bounds__(256) void k_split(const float* __restrict__ in,
                                               bf16* __restrict__ h, bf16* __restrict__ l) {
  size_t i = ((size_t)blockIdx.x * 256 + threadIdx.x) * 4;
  f32x4 v = *(const f32x4*)(in + i);
  bf16x4 hh, ll;
  #pragma unroll
  for (int j = 0; j < 4; ++j) {
    hh[j] = (bf16)v[j];
    ll[j] = (bf16)(v[j] - (float)hh[j]);
  }
  *(bf16x4*)(h + i) = hh;
  *(bf16x4*)(l + i) = ll;
}

// W_in split with zero-pad to 2304 rows
__global__ __launch_bounds__(256) void k_split_win(const float* __restrict__ W,
                                                   bf16* __restrict__ h, bf16* __restrict__ l) {
  int i = blockIdx.x * 256 + threadIdx.x;    // over 2304*512
  int row = i >> 9, col = i & 511;
  float v = (row < DPROJ) ? W[row * 512 + col] : 0.f;
  bf16 hh = (bf16)v;
  h[i] = hh;
  l[i] = (bf16)(v - (float)hh);
}

// Effective per-channel 3x3 kernels for the interleaved conv block (identity channel map).
__global__ void k_keff(const float* __restrict__ w33,
                       const float* __restrict__ w13x1, const float* __restrict__ w31x1,
                       const float* __restrict__ w13x2, const float* __restrict__ w31x2,
                       const float* __restrict__ w13bc1, const float* __restrict__ w31bc1,
                       const float* __restrict__ w13bc2, const float* __restrict__ w31bc2,
                       float* __restrict__ keff) {
  int j = blockIdx.x * 128 + threadIdx.x;
  if (j >= CONVD) return;
  float kh[3] = {0,0,0}, kw[3] = {0,0,0};
  bool dense = ((j & 1) == 0);
  if (!dense) {
    int m = j >> 2;                      // j = 4m+1 or 4m+3
    if ((j & 3) == 1) {
      if (m < 256) { for (int t=0;t<3;++t){ kh[t]=w31x1[m*3+t];  kw[t]=w13x1[m*3+t];  } }
      else { int q=m-256; for (int t=0;t<3;++t){ kh[t]=w31bc1[q*3+t]; kw[t]=w13bc1[q*3+t]; } }
    } else {
      if (m < 256) { for (int t=0;t<3;++t){ kh[t]=w31x2[m*3+t];  kw[t]=w13x2[m*3+t];  } }
      else { int q=m-256; for (int t=0;t<3;++t){ kh[t]=w31bc2[q*3+t]; kw[t]=w13bc2[q*3+t]; } }
    }
  }
  #pragma unroll
  for (int dh = 0; dh < 3; ++dh)
    #pragma unroll
    for (int dw = 0; dw < 3; ++dw) {
      float v = dense ? w33[(j >> 1) * 9 + dh*3 + dw] : kh[dh] * kw[dw];
      keff[(dh*3 + dw) * CONVD + j] = v;
    }
}

// ---- split-bf16 MFMA GEMM: C[M,N](f32) = (Ah+Al)(Bh+Bl)^T ≈ AhBh + AhBl + AlBh ----
// 128x128 tile, BK=32, 4 waves; 1-D grid, chunked-XCD swizzle, ntile-inner for A reuse.
__global__ __launch_bounds__(256) void k_gemm3(const bf16* __restrict__ Ah, const bf16* __restrict__ Al, int lda,
                                               const bf16* __restrict__ Bh, const bf16* __restrict__ Bl, int ldb,
                                               float* __restrict__ C, int ldc,
                                               int K, int NW, int ntn) {
  __shared__ __align__(16) bf16 Ash[128 * 32];
  __shared__ __align__(16) bf16 Asl[128 * 32];
  __shared__ __align__(16) bf16 Bsh[128 * 32];
  __shared__ __align__(16) bf16 Bsl[128 * 32];

  // bijective chunked XCD swizzle (m204): consecutive logical ids share an XCD
  int nwg = gridDim.x, bid = blockIdx.x;
  int q = nwg >> 3, r = nwg & 7;
  int xcd = bid & 7, loc = bid >> 3;
  int wg  = (xcd < r ? xcd * (q + 1) : r * (q + 1) + (xcd - r) * q) + loc;
  long m0 = (long)(wg / ntn) * 128;
  long n0 = (long)(wg % ntn) * 128;

  const int tid  = threadIdx.x;
  const int w    = tid >> 6, lane = tid & 63;
  const int wr   = w >> 1, wc = w & 1;

  f32x4 acc[4][4];
  #pragma unroll
  for (int i = 0; i < 4; ++i)
    #pragma unroll
    for (int j = 0; j < 4; ++j) acc[i][j] = (f32x4){0.f,0.f,0.f,0.f};

  const int srow = w * 16 + (lane >> 2);   // staging row within 64-row half
  const int scol = (lane & 3) * 8;         // 8 bf16 = 16B per lane
  const long aoff = (m0 + srow) * (long)lda + scol;
  const long boff = (n0 + srow) * (long)ldb + scol;
  const int fr = lane & 15;
  const int kc = (lane >> 4) * 8;

  for (int k0 = 0; k0 < K; k0 += 32) {
    #pragma unroll
    for (int i = 0; i < 2; ++i) {
      long ao = aoff + (long)i*64*lda + k0;
      long bo = boff + (long)i*64*ldb + k0;
      int ls = (i*4 + w) * 512;
      __builtin_amdgcn_global_load_lds((const __attribute__((address_space(1))) void*)(Ah + ao),
                                       (__attribute__((address_space(3))) void*)&Ash[ls], 16, 0, 0);
      __builtin_amdgcn_global_load_lds((const __attribute__((address_space(1))) void*)(Al + ao),
                                       (__attribute__((address_space(3))) void*)&Asl[ls], 16, 0, 0);
      __builtin_amdgcn_global_load_lds((const __attribute__((address_space(1))) void*)(Bh + bo),
                                       (__attribute__((address_space(3))) void*)&Bsh[ls], 16, 0, 0);
      __builtin_amdgcn_global_load_lds((const __attribute__((address_space(1))) void*)(Bl + bo),
                                       (__attribute__((address_space(3))) void*)&Bsl[ls], 16, 0, 0);
    }
    __syncthreads();
    bf16x8 ah[4], al[4], bh[4], bl[4];
    #pragma unroll
    for (int f = 0; f < 4; ++f) {
      int ar = (wr*64 + f*16 + fr) * 32 + kc;
      int br = (wc*64 + f*16 + fr) * 32 + kc;
      ah[f] = *(const bf16x8*)&Ash[ar];
      al[f] = *(const bf16x8*)&Asl[ar];
      bh[f] = *(const bf16x8*)&Bsh[br];
      bl[f] = *(const bf16x8*)&Bsl[br];
    }
    #pragma unroll
    for (int i = 0; i < 4; ++i)
      #pragma unroll
      for (int j = 0; j < 4; ++j) {
        acc[i][j] = __builtin_amdgcn_mfma_f32_16x16x32_bf16(ah[i], bh[j], acc[i][j], 0, 0, 0);
        acc[i][j] = __builtin_amdgcn_mfma_f32_16x16x32_bf16(ah[i], bl[j], acc[i][j], 0, 0, 0);
        acc[i][j] = __builtin_amdgcn_mfma_f32_16x16x32_bf16(al[i], bh[j], acc[i][j], 0, 0, 0);
      }
    __syncthreads();
  }

  const int cr = (lane >> 4) * 4;          // C/D: row=(lane>>4)*4+reg, col=lane&15
  const int cc = lane & 15;
  #pragma unroll
  for (int i = 0; i < 4; ++i) {
    long rbase = m0 + wr*64 + i*16 + cr;
    #pragma unroll
    for (int j = 0; j < 4; ++j) {
      int col = (int)n0 + wc*64 + j*16 + cc;
      if (col < NW) {
        float* cp = C + rbase * (long)ldc + col;
        #pragma unroll
        for (int r = 0; r < 4; ++r) cp[(long)r * ldc] = acc[i][j][r];
      }
    }
  }
}

// ---------------- depthwise 3x3 over xBC slice -> xbc fp32 (with silu) ----------------
__global__ __launch_bounds__(256) void k_conv_xbc(const float* __restrict__ zx,
                                                  const float* __restrict__ keff,
                                                  float* __restrict__ out) {
  int l = blockIdx.x;                        // chunk-local token
  int c = blockIdx.y * 256 + threadIdx.x;
  if (c >= CONVD) return;
  int h = (l >> 6) & 63, wq = l & 63;
  long base = (long)l * DPROJ + DIN + c;
  float acc = 0.f;
  #pragma unroll
  for (int dh = 0; dh < 3; ++dh) {
    int hh = h + dh - 1;
    if (hh < 0 || hh >= HDIM) continue;
    #pragma unroll
    for (int dw = 0; dw < 3; ++dw) {
      int ww = wq + dw - 1;
      if (ww < 0 || ww >= WDIM) continue;
      acc = fmaf(zx[base + (long)((dh-1)*WDIM + (dw-1)) * DPROJ],
                 keff[(dh*3 + dw) * CONVD + c], acc);
    }
  }
  out[(long)l * CONVD + c] = siluf(acc);
}

// ------- depthwise 3x3 over z slice -> g2 cols [1024,2048) as hi/lo (silu * alpha2) -------
__global__ __launch_bounds__(256) void k_conv_z(const float* __restrict__ zx,
                                                const float* __restrict__ wz,
                                                const float* __restrict__ a2_p,
                                                bf16* __restrict__ g2h, bf16* __restrict__ g2l) {
  int l = blockIdx.x;
  int c = blockIdx.y * 256 + threadIdx.x;    // < 1024
  int h = (l >> 6) & 63, wq = l & 63;
  long base = (long)l * DPROJ + c;
  float acc = 0.f;
  #pragma unroll
  for (int dh = 0; dh < 3; ++dh) {
    int hh = h + dh - 1;
    if (hh < 0 || hh >= HDIM) continue;
    #pragma unroll
    for (int dw = 0; dw < 3; ++dw) {
      int ww = wq + dw - 1;
      if (ww < 0 || ww >= WDIM) continue;
      acc = fmaf(zx[base + (long)((dh-1)*WDIM + (dw-1)) * DPROJ],
                 wz[c*9 + dh*3 + dw], acc);
    }
  }
  float v = a2_p[0] * siluf(acc);
  bf16 hh2 = (bf16)v;
  long o = (long)l * 2048 + 1024 + c;
  g2h[o] = hh2;
  g2l[o] = (bf16)(v - (float)hh2);
}

// ---------------- dA = softplus(dt_raw + dt_bias) * exp(A_log) ----------------
__global__ __launch_bounds__(256) void k_dA(const float* __restrict__ zx,
                                            const float* __restrict__ dt_bias,
                                            const float* __restrict__ A_log,
                                            float* __restrict__ dA) {
  int idx = blockIdx.x * 256 + threadIdx.x;
  int hd = idx & 127;
  long row = (long)(idx >> 7);
  float x = zx[row * DPROJ + 2112 + hd] + dt_bias[hd];
  float sp = (x > 20.f) ? x : log1pf(__expf(x));
  dA[idx] = sp * __expf(A_log[hd]);
}

// ---------------- KV partials over 128-token slices, then reduce ----------------
__global__ __launch_bounds__(512) void k_kv_part(const float* __restrict__ xbc,
                                                 const float* __restrict__ dA,
                                                 float* __restrict__ part) {
  int t = threadIdx.x;
  int m = t >> 3, p = t & 7;                 // m: head-pair 0..63, p: headdim 0..7
  int lc = blockIdx.x, b = blockIdx.y;       // b chunk-local
  float acc0[16], acc1[16];
  #pragma unroll
  for (int s = 0; s < 16; ++s) { acc0[s] = 0.f; acc1[s] = 0.f; }
  long lbase = (long)b * LPB + lc * 128;
  for (int li = 0; li < 128; ++li) {
    long row = lbase + li;
    const float* xr = xbc + row * CONVD;
    float a0 = dA[row * 128 + 2*m];
    float a1 = dA[row * 128 + 2*m + 1];
    float xv0 = xr[16*m + p]     * a0;   // head 2m   (group 0)
    float xv1 = xr[16*m + 8 + p] * a1;   // head 2m+1 (group 1)
    const float* Br = xr + DIN;          // Bm, uniform across threads
    #pragma unroll
    for (int s = 0; s < 16; ++s) {
      acc0[s] = fmaf(Br[s],      xv0, acc0[s]);
      acc1[s] = fmaf(Br[16 + s], xv1, acc1[s]);
    }
  }
  long base = ((long)(b*32 + lc)) * 16384 + (long)m * 256;
  #pragma unroll
  for (int s = 0; s < 16; ++s) {
    part[base + s*8 + p]       = acc0[s];
    part[base + 128 + s*8 + p] = acc1[s];
  }
}

__global__ __launch_bounds__(256) void k_kv_red(const float* __restrict__ part,
                                                float* __restrict__ KV) {
  int e = blockIdx.x * 256 + threadIdx.x;   // 16384 per b
  int b = blockIdx.y;
  float s = 0.f;
  #pragma unroll 4
  for (int lc = 0; lc < 32; ++lc) s += part[((long)(b*32 + lc)) * 16384 + e];
  KV[(long)b * 16384 + e] = s;
}

// --- y = Q*KV + x*Dp, LayerNorm, scale/shift, *alpha1 -> g2 cols [0,1024) hi/lo ---
__global__ __launch_bounds__(256) void k_y_ln(const float* __restrict__ xbc,
                                              const float* __restrict__ KV,
                                              const float* __restrict__ Dp,
                                              const float* __restrict__ ln_g,
                                              const float* __restrict__ ln_b,
                                              const float* __restrict__ sc_p,
                                              const float* __restrict__ sh_p,
                                              const float* __restrict__ a1_p,
                                              bf16* __restrict__ g2h, bf16* __restrict__ g2l) {
  __shared__ float Qs[64][32];
  __shared__ float red[8];
  int t = threadIdx.x;
  int hd = t >> 1, pb = (t & 1) * 4;
  int m = hd >> 1, g = hd & 1;
  int b = blockIdx.x >> 6;                  // chunk-local batch
  long l0 = (long)b * LPB + (blockIdx.x & 63) * 64;

  f32x4 kv[16];
  #pragma unroll
  for (int s = 0; s < 16; ++s)
    kv[s] = *(const f32x4*)&KV[(long)b * 16384 + m*256 + g*128 + s*8 + pb];

  for (int i = t; i < 64*32; i += 256) {
    int tok = i >> 5, q = i & 31;
    Qs[tok][q] = xbc[(l0 + tok) * CONVD + 1056 + q];
  }
  int c0 = hd*8 + pb;
  f32x4 lg = *(const f32x4*)&ln_g[c0];
  f32x4 lb = *(const f32x4*)&ln_b[c0];
  float dpv = Dp[hd];
  float sc = sc_p[0], sh = sh_p[0], a1 = a1_p[0];
  int wv = t >> 6, lane = t & 63;
  __syncthreads();

  for (int tok = 0; tok < 64; ++tok) {
    long row = l0 + tok;
    f32x4 xv = *(const f32x4*)&xbc[row * CONVD + c0];
    f32x4 yv;
    #pragma unroll
    for (int j = 0; j < 4; ++j) yv[j] = xv[j] * dpv;
    #pragma unroll
    for (int s = 0; s < 16; ++s) {
      float qv = Qs[tok][g*16 + s];
      #pragma unroll
      for (int j = 0; j < 4; ++j) yv[j] = fmaf(qv, kv[s][j], yv[j]);
    }
    float s1 = yv[0] + yv[1] + yv[2] + yv[3];
    float s2 = yv[0]*yv[0] + yv[1]*yv[1] + yv[2]*yv[2] + yv[3]*yv[3];
    #pragma unroll
    for (int off = 1; off < 64; off <<= 1) {
      s1 += __shfl_xor(s1, off, 64);
      s2 += __shfl_xor(s2, off, 64);
    }
    if (lane == 0) { red[wv*2] = s1; red[wv*2 + 1] = s2; }
    __syncthreads();
    float S1 = red[0] + red[2] + red[4] + red[6];
    float S2 = red[1] + red[3] + red[5] + red[7];
    float mu   = S1 * (1.f/1024.f);
    float var  = S2 * (1.f/1024.f) - mu*mu;
    float rstd = rsqrtf(var + 1e-5f);
    bf16x4 h4, l4;
    #pragma unroll
    for (int j = 0; j < 4; ++j) {
      float yn = (yv[j] - mu) * rstd * lg[j] + lb[j];
      yn = a1 * (yn * sc + sh);
      h4[j] = (bf16)yn;
      l4[j] = (bf16)(yn - (float)h4[j]);
    }
    *(bf16x4*)&g2h[row * 2048 + c0] = h4;
    *(bf16x4*)&g2l[row * 2048 + c0] = l4;
    __syncthreads();   // protect red[] before next token
  }
}

// ---------------- host launcher ----------------
extern "C" void kernel_launch(void* const* d_in, const int* in_sizes, int n_in,
                              void* d_out, int out_size, void* d_ws, size_t ws_size,
                              hipStream_t stream) {
  const float* u       = (const float*)d_in[0];
  const float* W_in    = (const float*)d_in[3];
  const float* dt_bias = (const float*)d_in[4];
  const float* A_log   = (const float*)d_in[5];
  const float* Dp      = (const float*)d_in[6];
  const float* w33     = (const float*)d_in[7];
  const float* w13x1   = (const float*)d_in[8];
  const float* w31x1   = (const float*)d_in[9];
  const float* w13x2   = (const float*)d_in[10];
  const float* w31x2   = (const float*)d_in[11];
  const float* w13bc1  = (const float*)d_in[12];
  const float* w31bc1  = (const float*)d_in[13];
  const float* w13bc2  = (const float*)d_in[14];
  const float* w31bc2  = (const float*)d_in[15];
  const float* wz      = (const float*)d_in[16];
  const float* ln_g    = (const float*)d_in[17];
  const float* ln_b    = (const float*)d_in[18];
  const float* sc      = (const float*)d_in[19];
  const float* sh      = (const float*)d_in[20];
  const float* a1      = (const float*)d_in[21];
  const float* a2      = (const float*)d_in[22];
  const float* W_out   = (const float*)d_in[23];

  // per-batch buffer bytes
  const size_t B_U    = 4194304;    // 4096x512 bf16 (each of hi/lo)
  const size_t B_G2   = 16777216;   // 4096x2048 bf16 (each of hi/lo)
  const size_t B_ZX   = 36700160;   // 4096x2240 f32
  const size_t B_XBC  = 17825792;   // 4096x1088 f32
  const size_t B_DA   = 2097152;    // 4096x128 f32
  const size_t B_PART = 2097152;    // 32x16384 f32
  const size_t B_KV   = 65536;      // 16384 f32
  const size_t perC   = 2*B_G2 + B_ZX + B_XBC + B_DA + B_PART + B_KV;  // u aliases g2
  const size_t persist = 2*2359296 + 2*2097152 + 40960;

  int C = 8;
  while (C > 1 && persist + (size_t)C * perC > ws_size) C >>= 1;
  const int nch = 8 / C;
  const int Mc  = C * LPB;

  char* p = (char*)d_ws;
  bf16*  win_h  = (bf16*)p;  p += 2359296;   // 2304x512
  bf16*  win_l  = (bf16*)p;  p += 2359296;
  bf16*  wout_h = (bf16*)p;  p += 2097152;   // 512x2048
  bf16*  wout_l = (bf16*)p;  p += 2097152;
  float* keff   = (float*)p; p += 40960;
  char*  arena  = p;                          // u hi/lo aliases g2 hi/lo
  bf16*  g2h    = (bf16*)arena;
  bf16*  g2l    = (bf16*)(arena + (size_t)C * B_G2);
  bf16*  u_h    = (bf16*)arena;
  bf16*  u_l    = (bf16*)(arena + (size_t)C * B_U);
  p = arena + (size_t)2 * C * B_G2;
  float* zx     = (float*)p; p += (size_t)C * B_ZX;
  float* xbc    = (float*)p; p += (size_t)C * B_XBC;
  float* dAb    = (float*)p; p += (size_t)C * B_DA;
  float* part   = (float*)p; p += (size_t)C * B_PART;
  float* KV     = (float*)p; p += (size_t)C * B_KV;

  k_split_win<<<4608, 256, 0, stream>>>(W_in, win_h, win_l);
  k_split    <<<1024, 256, 0, stream>>>(W_out, wout_h, wout_l);   // 512*2048/1024
  k_keff     <<<9, 128, 0, stream>>>(w33, w13x1, w31x1, w13x2, w31x2,
                                     w13bc1, w31bc1, w13bc2, w31bc2, keff);

  for (int ch = 0; ch < nch; ++ch) {
    const float* uc   = u + (size_t)ch * Mc * 512;
    float*       outc = (float*)d_out + (size_t)ch * Mc * 512;

    k_split<<<Mc/2, 256, 0, stream>>>(uc, u_h, u_l);   // Mc*512/1024 blocks

    // GEMM1: zx = u @ W_in^T (fp32-grade, N padded to 2304, store-guard 2240)
    k_gemm3<<<(Mc/128)*18, 256, 0, stream>>>(u_h, u_l, 512, win_h, win_l, 512,
                                             zx, DPROJ, 512, DPROJ, 18);

    k_dA      <<<Mc/2, 256, 0, stream>>>(zx, dt_bias, A_log, dAb);
    k_conv_xbc<<<dim3(Mc, 5), 256, 0, stream>>>(zx, keff, xbc);
    k_conv_z  <<<dim3(Mc, 4), 256, 0, stream>>>(zx, wz, a2, g2h, g2l);

    k_kv_part <<<dim3(32, C), 512, 0, stream>>>(xbc, dAb, part);
    k_kv_red  <<<dim3(64, C), 256, 0, stream>>>(part, KV);
    k_y_ln    <<<C*64, 256, 0, stream>>>(xbc, KV, Dp, ln_g, ln_b, sc, sh, a1, g2h, g2l);

    // GEMM2: out = g2 @ W_out^T (K=2048, single split GEMM)
    k_gemm3<<<(Mc/128)*4, 256, 0, stream>>>(g2h, g2l, 2048, wout_h, wout_l, 2048,
                                            outc, 512, 2048, 512, 4);
  }
}

// Round 4
// 1505.963 us; speedup vs baseline: 1.0455x; 1.0455x over previous
//
#include <hip/hip_runtime.h>
#include <hip/hip_bf16.h>
#include <cstdint>
#include <cstddef>

// ---------------- problem constants ----------------
#define HDIM    64
#define WDIM    64
#define LPB     4096            // tokens per batch
#define DMODEL  512
#define DIN     1024
#define CONVD   1088
#define DPROJ   2240            // 2*DIN + 2*32 + 128
#define NHEADS  128

using bf16   = __bf16;
using bf16x8 = __attribute__((ext_vector_type(8))) __bf16;
using bf16x4 = __attribute__((ext_vector_type(4))) __bf16;
using f32x4  = __attribute__((ext_vector_type(4))) float;

__device__ __forceinline__ float siluf(float x) { return x / (1.f + __expf(-x)); }

// ---------------- hi/lo split prep ----------------
__global__ __launch_bounds__(256) void k_split(const float* __restrict__ in,
                                               bf16* __restrict__ h, bf16* __restrict__ l) {
  size_t i = ((size_t)blockIdx.x * 256 + threadIdx.x) * 4;
  f32x4 v = *(const f32x4*)(in + i);
  bf16x4 hh, ll;
  #pragma unroll
  for (int j = 0; j < 4; ++j) {
    hh[j] = (bf16)v[j];
    ll[j] = (bf16)(v[j] - (float)hh[j]);
  }
  *(bf16x4*)(h + i) = hh;
  *(bf16x4*)(l + i) = ll;
}

// W_in split with zero-pad to 2304 rows
__global__ __launch_bounds__(256) void k_split_win(const float* __restrict__ W,
                                                   bf16* __restrict__ h, bf16* __restrict__ l) {
  int i = blockIdx.x * 256 + threadIdx.x;    // over 2304*512
  int row = i >> 9, col = i & 511;
  float v = (row < DPROJ) ? W[row * 512 + col] : 0.f;
  bf16 hh = (bf16)v;
  h[i] = hh;
  l[i] = (bf16)(v - (float)hh);
}

// Effective per-channel 3x3 kernels for the interleaved conv block (identity channel map).
__global__ void k_keff(const float* __restrict__ w33,
                       const float* __restrict__ w13x1, const float* __restrict__ w31x1,
                       const float* __restrict__ w13x2, const float* __restrict__ w31x2,
                       const float* __restrict__ w13bc1, const float* __restrict__ w31bc1,
                       const float* __restrict__ w13bc2, const float* __restrict__ w31bc2,
                       float* __restrict__ keff) {
  int j = blockIdx.x * 128 + threadIdx.x;
  if (j >= CONVD) return;
  float kh[3] = {0,0,0}, kw[3] = {0,0,0};
  bool dense = ((j & 1) == 0);
  if (!dense) {
    int m = j >> 2;                      // j = 4m+1 or 4m+3
    if ((j & 3) == 1) {
      if (m < 256) { for (int t=0;t<3;++t){ kh[t]=w31x1[m*3+t];  kw[t]=w13x1[m*3+t];  } }
      else { int q=m-256; for (int t=0;t<3;++t){ kh[t]=w31bc1[q*3+t]; kw[t]=w13bc1[q*3+t]; } }
    } else {
      if (m < 256) { for (int t=0;t<3;++t){ kh[t]=w31x2[m*3+t];  kw[t]=w13x2[m*3+t];  } }
      else { int q=m-256; for (int t=0;t<3;++t){ kh[t]=w31bc2[q*3+t]; kw[t]=w13bc2[q*3+t]; } }
    }
  }
  #pragma unroll
  for (int dh = 0; dh < 3; ++dh)
    #pragma unroll
    for (int dw = 0; dw < 3; ++dw) {
      float v = dense ? w33[(j >> 1) * 9 + dh*3 + dw] : kh[dh] * kw[dw];
      keff[(dh*3 + dw) * CONVD + j] = v;
    }
}

// ---- split-bf16 MFMA GEMM with optional split-K:
// C_part[kseg] [M,N](f32) = (Ah+Al)(Bh+Bl)^T over K-range [kseg*Kseg, (kseg+1)*Kseg)
// 128x128 tile, BK=32, 4 waves; 1-D grid = ntmn*ks, chunked-XCD swizzle, nt-inner.
__global__ __launch_bounds__(256) void k_gemm3(const bf16* __restrict__ Ah, const bf16* __restrict__ Al, int lda,
                                               const bf16* __restrict__ Bh, const bf16* __restrict__ Bl, int ldb,
                                               float* __restrict__ C, int ldc,
                                               int Kseg, int NW, int ntn, int ntmn, long Cseg) {
  __shared__ __align__(16) bf16 Ash[128 * 32];
  __shared__ __align__(16) bf16 Asl[128 * 32];
  __shared__ __align__(16) bf16 Bsh[128 * 32];
  __shared__ __align__(16) bf16 Bsl[128 * 32];

  // bijective chunked XCD swizzle (m204)
  int nwg = gridDim.x, bid = blockIdx.x;
  int q = nwg >> 3, r = nwg & 7;
  int xcd = bid & 7, loc = bid >> 3;
  int wg  = (xcd < r ? xcd * (q + 1) : r * (q + 1) + (xcd - r) * q) + loc;
  int kseg = wg / ntmn;
  int rem  = wg - kseg * ntmn;
  long m0 = (long)(rem / ntn) * 128;
  long n0 = (long)(rem % ntn) * 128;
  const int kbase = kseg * Kseg;

  const int tid  = threadIdx.x;
  const int w    = tid >> 6, lane = tid & 63;
  const int wr   = w >> 1, wc = w & 1;

  f32x4 acc[4][4];
  #pragma unroll
  for (int i = 0; i < 4; ++i)
    #pragma unroll
    for (int j = 0; j < 4; ++j) acc[i][j] = (f32x4){0.f,0.f,0.f,0.f};

  const int srow = w * 16 + (lane >> 2);   // staging row within 64-row half
  const int scol = (lane & 3) * 8;         // 8 bf16 = 16B per lane
  const long aoff = (m0 + srow) * (long)lda + scol + kbase;
  const long boff = (n0 + srow) * (long)ldb + scol + kbase;
  const int fr = lane & 15;
  const int kc = (lane >> 4) * 8;

  for (int k0 = 0; k0 < Kseg; k0 += 32) {
    #pragma unroll
    for (int i = 0; i < 2; ++i) {
      long ao = aoff + (long)i*64*lda + k0;
      long bo = boff + (long)i*64*ldb + k0;
      int ls = (i*4 + w) * 512;
      __builtin_amdgcn_global_load_lds((const __attribute__((address_space(1))) void*)(Ah + ao),
                                       (__attribute__((address_space(3))) void*)&Ash[ls], 16, 0, 0);
      __builtin_amdgcn_global_load_lds((const __attribute__((address_space(1))) void*)(Al + ao),
                                       (__attribute__((address_space(3))) void*)&Asl[ls], 16, 0, 0);
      __builtin_amdgcn_global_load_lds((const __attribute__((address_space(1))) void*)(Bh + bo),
                                       (__attribute__((address_space(3))) void*)&Bsh[ls], 16, 0, 0);
      __builtin_amdgcn_global_load_lds((const __attribute__((address_space(1))) void*)(Bl + bo),
                                       (__attribute__((address_space(3))) void*)&Bsl[ls], 16, 0, 0);
    }
    __syncthreads();
    bf16x8 ah[4], al[4], bh[4], bl[4];
    #pragma unroll
    for (int f = 0; f < 4; ++f) {
      int ar = (wr*64 + f*16 + fr) * 32 + kc;
      int br = (wc*64 + f*16 + fr) * 32 + kc;
      ah[f] = *(const bf16x8*)&Ash[ar];
      al[f] = *(const bf16x8*)&Asl[ar];
      bh[f] = *(const bf16x8*)&Bsh[br];
      bl[f] = *(const bf16x8*)&Bsl[br];
    }
    #pragma unroll
    for (int i = 0; i < 4; ++i)
      #pragma unroll
      for (int j = 0; j < 4; ++j) {
        acc[i][j] = __builtin_amdgcn_mfma_f32_16x16x32_bf16(ah[i], bh[j], acc[i][j], 0, 0, 0);
        acc[i][j] = __builtin_amdgcn_mfma_f32_16x16x32_bf16(ah[i], bl[j], acc[i][j], 0, 0, 0);
        acc[i][j] = __builtin_amdgcn_mfma_f32_16x16x32_bf16(al[i], bh[j], acc[i][j], 0, 0, 0);
      }
    __syncthreads();
  }

  float* Cb = C + (long)kseg * Cseg;
  const int cr = (lane >> 4) * 4;          // C/D: row=(lane>>4)*4+reg, col=lane&15
  const int cc = lane & 15;
  #pragma unroll
  for (int i = 0; i < 4; ++i) {
    long rbase = m0 + wr*64 + i*16 + cr;
    #pragma unroll
    for (int j = 0; j < 4; ++j) {
      int col = (int)n0 + wc*64 + j*16 + cc;
      if (col < NW) {
        float* cp = Cb + rbase * (long)ldc + col;
        #pragma unroll
        for (int r = 0; r < 4; ++r) cp[(long)r * ldc] = acc[i][j][r];
      }
    }
  }
}

// ---------------- split-K reduction: out = sum of 4 partials ----------------
__global__ __launch_bounds__(256) void k_red4(const float* __restrict__ part, long seg,
                                              float* __restrict__ out) {
  long i = ((long)blockIdx.x * 256 + threadIdx.x) * 4;
  f32x4 s0 = *(const f32x4*)(part + i);
  f32x4 s1 = *(const f32x4*)(part + seg + i);
  f32x4 s2 = *(const f32x4*)(part + 2*seg + i);
  f32x4 s3 = *(const f32x4*)(part + 3*seg + i);
  f32x4 o;
  #pragma unroll
  for (int j = 0; j < 4; ++j) o[j] = (s0[j] + s1[j]) + (s2[j] + s3[j]);
  *(f32x4*)(out + i) = o;
}

// ------ fused: depthwise 3x3 z->g2 hi/lo | depthwise 3x3 xBC->xbc | dt->dA ------
__global__ __launch_bounds__(256) void k_conv_all(const float* __restrict__ zx,
                                                  const float* __restrict__ keff,
                                                  const float* __restrict__ wz,
                                                  const float* __restrict__ a2_p,
                                                  const float* __restrict__ dt_bias,
                                                  const float* __restrict__ A_log,
                                                  float* __restrict__ xbc,
                                                  bf16* __restrict__ g2h, bf16* __restrict__ g2l,
                                                  float* __restrict__ dAb) {
  int l = blockIdx.x;
  int c = blockIdx.y * 256 + threadIdx.x;    // global zx column, < 2304
  int h = (l >> 6) & 63, wq = l & 63;

  if (c < 2112) {
    // conv path (z: c<1024 with wz; xBC: 1024<=c<2112 with keff)
    long base = (long)l * DPROJ + c;
    float acc = 0.f;
    #pragma unroll
    for (int dh = 0; dh < 3; ++dh) {
      int hh = h + dh - 1;
      if (hh < 0 || hh >= HDIM) continue;
      #pragma unroll
      for (int dw = 0; dw < 3; ++dw) {
        int ww = wq + dw - 1;
        if (ww < 0 || ww >= WDIM) continue;
        float wgt = (c < 1024) ? wz[c*9 + dh*3 + dw]
                               : keff[(dh*3 + dw) * CONVD + (c - 1024)];
        acc = fmaf(zx[base + (long)((dh-1)*WDIM + (dw-1)) * DPROJ], wgt, acc);
      }
    }
    if (c < 1024) {
      float v = a2_p[0] * siluf(acc);
      bf16 hh2 = (bf16)v;
      long o = (long)l * 2048 + 1024 + c;
      g2h[o] = hh2;
      g2l[o] = (bf16)(v - (float)hh2);
    } else {
      xbc[(long)l * CONVD + (c - 1024)] = siluf(acc);
    }
  } else if (c < 2240) {
    int hd = c - 2112;
    float x = zx[(long)l * DPROJ + c] + dt_bias[hd];
    float sp = (x > 20.f) ? x : log1pf(__expf(x));
    dAb[(long)l * 128 + hd] = sp * __expf(A_log[hd]);
  }
}

// ---------------- KV partials over 128-token slices, then reduce ----------------
__global__ __launch_bounds__(512) void k_kv_part(const float* __restrict__ xbc,
                                                 const float* __restrict__ dA,
                                                 float* __restrict__ part) {
  int t = threadIdx.x;
  int m = t >> 3, p = t & 7;                 // m: head-pair 0..63, p: headdim 0..7
  int lc = blockIdx.x, b = blockIdx.y;       // b chunk-local
  float acc0[16], acc1[16];
  #pragma unroll
  for (int s = 0; s < 16; ++s) { acc0[s] = 0.f; acc1[s] = 0.f; }
  long lbase = (long)b * LPB + lc * 128;
  for (int li = 0; li < 128; ++li) {
    long row = lbase + li;
    const float* xr = xbc + row * CONVD;
    float a0 = dA[row * 128 + 2*m];
    float a1 = dA[row * 128 + 2*m + 1];
    float xv0 = xr[16*m + p]     * a0;   // head 2m   (group 0)
    float xv1 = xr[16*m + 8 + p] * a1;   // head 2m+1 (group 1)
    const float* Br = xr + DIN;          // Bm, uniform across threads
    #pragma unroll
    for (int s = 0; s < 16; ++s) {
      acc0[s] = fmaf(Br[s],      xv0, acc0[s]);
      acc1[s] = fmaf(Br[16 + s], xv1, acc1[s]);
    }
  }
  long base = ((long)(b*32 + lc)) * 16384 + (long)m * 256;
  #pragma unroll
  for (int s = 0; s < 16; ++s) {
    part[base + s*8 + p]       = acc0[s];
    part[base + 128 + s*8 + p] = acc1[s];
  }
}

__global__ __launch_bounds__(256) void k_kv_red(const float* __restrict__ part,
                                                float* __restrict__ KV) {
  int e = blockIdx.x * 256 + threadIdx.x;   // 16384 per b
  int b = blockIdx.y;
  float s = 0.f;
  #pragma unroll 4
  for (int lc = 0; lc < 32; ++lc) s += part[((long)(b*32 + lc)) * 16384 + e];
  KV[(long)b * 16384 + e] = s;
}

// --- y = Q*KV + x*Dp, LayerNorm, scale/shift, *alpha1 -> g2 cols [0,1024) hi/lo ---
__global__ __launch_bounds__(256) void k_y_ln(const float* __restrict__ xbc,
                                              const float* __restrict__ KV,
                                              const float* __restrict__ Dp,
                                              const float* __restrict__ ln_g,
                                              const float* __restrict__ ln_b,
                                              const float* __restrict__ sc_p,
                                              const float* __restrict__ sh_p,
                                              const float* __restrict__ a1_p,
                                              bf16* __restrict__ g2h, bf16* __restrict__ g2l) {
  __shared__ float Qs[64][32];
  __shared__ float red[8];
  int t = threadIdx.x;
  int hd = t >> 1, pb = (t & 1) * 4;
  int m = hd >> 1, g = hd & 1;
  int b = blockIdx.x >> 6;                  // chunk-local batch
  long l0 = (long)b * LPB + (blockIdx.x & 63) * 64;

  f32x4 kv[16];
  #pragma unroll
  for (int s = 0; s < 16; ++s)
    kv[s] = *(const f32x4*)&KV[(long)b * 16384 + m*256 + g*128 + s*8 + pb];

  for (int i = t; i < 64*32; i += 256) {
    int tok = i >> 5, q = i & 31;
    Qs[tok][q] = xbc[(l0 + tok) * CONVD + 1056 + q];
  }
  int c0 = hd*8 + pb;
  f32x4 lg = *(const f32x4*)&ln_g[c0];
  f32x4 lb = *(const f32x4*)&ln_b[c0];
  float dpv = Dp[hd];
  float sc = sc_p[0], sh = sh_p[0], a1 = a1_p[0];
  int wv = t >> 6, lane = t & 63;
  __syncthreads();

  for (int tok = 0; tok < 64; ++tok) {
    long row = l0 + tok;
    f32x4 xv = *(const f32x4*)&xbc[row * CONVD + c0];
    f32x4 yv;
    #pragma unroll
    for (int j = 0; j < 4; ++j) yv[j] = xv[j] * dpv;
    #pragma unroll
    for (int s = 0; s < 16; ++s) {
      float qv = Qs[tok][g*16 + s];
      #pragma unroll
      for (int j = 0; j < 4; ++j) yv[j] = fmaf(qv, kv[s][j], yv[j]);
    }
    float s1 = yv[0] + yv[1] + yv[2] + yv[3];
    float s2 = yv[0]*yv[0] + yv[1]*yv[1] + yv[2]*yv[2] + yv[3]*yv[3];
    #pragma unroll
    for (int off = 1; off < 64; off <<= 1) {
      s1 += __shfl_xor(s1, off, 64);
      s2 += __shfl_xor(s2, off, 64);
    }
    if (lane == 0) { red[wv*2] = s1; red[wv*2 + 1] = s2; }
    __syncthreads();
    float S1 = red[0] + red[2] + red[4] + red[6];
    float S2 = red[1] + red[3] + red[5] + red[7];
    float mu   = S1 * (1.f/1024.f);
    float var  = S2 * (1.f/1024.f) - mu*mu;
    float rstd = rsqrtf(var + 1e-5f);
    bf16x4 h4, l4;
    #pragma unroll
    for (int j = 0; j < 4; ++j) {
      float yn = (yv[j] - mu) * rstd * lg[j] + lb[j];
      yn = a1 * (yn * sc + sh);
      h4[j] = (bf16)yn;
      l4[j] = (bf16)(yn - (float)h4[j]);
    }
    *(bf16x4*)&g2h[row * 2048 + c0] = h4;
    *(bf16x4*)&g2l[row * 2048 + c0] = l4;
    __syncthreads();   // protect red[] before next token
  }
}

// ---------------- host launcher ----------------
extern "C" void kernel_launch(void* const* d_in, const int* in_sizes, int n_in,
                              void* d_out, int out_size, void* d_ws, size_t ws_size,
                              hipStream_t stream) {
  const float* u       = (const float*)d_in[0];
  const float* W_in    = (const float*)d_in[3];
  const float* dt_bias = (const float*)d_in[4];
  const float* A_log   = (const float*)d_in[5];
  const float* Dp      = (const float*)d_in[6];
  const float* w33     = (const float*)d_in[7];
  const float* w13x1   = (const float*)d_in[8];
  const float* w31x1   = (const float*)d_in[9];
  const float* w13x2   = (const float*)d_in[10];
  const float* w31x2   = (const float*)d_in[11];
  const float* w13bc1  = (const float*)d_in[12];
  const float* w31bc1  = (const float*)d_in[13];
  const float* w13bc2  = (const float*)d_in[14];
  const float* w31bc2  = (const float*)d_in[15];
  const float* wz      = (const float*)d_in[16];
  const float* ln_g    = (const float*)d_in[17];
  const float* ln_b    = (const float*)d_in[18];
  const float* sc      = (const float*)d_in[19];
  const float* sh      = (const float*)d_in[20];
  const float* a1      = (const float*)d_in[21];
  const float* a2      = (const float*)d_in[22];
  const float* W_out   = (const float*)d_in[23];

  // per-batch buffer bytes
  const size_t B_U    = 4194304;    // 4096x512 bf16 (each of hi/lo)
  const size_t B_G2   = 16777216;   // 4096x2048 bf16 (each of hi/lo)
  const size_t B_ZX   = 36700160;   // 4096x2240 f32 (also hosts 4x split-K partials)
  const size_t B_XBC  = 17825792;   // 4096x1088 f32
  const size_t B_DA   = 2097152;    // 4096x128 f32
  const size_t B_PART = 2097152;    // 32x16384 f32
  const size_t B_KV   = 65536;      // 16384 f32
  const size_t perC   = 2*B_G2 + B_ZX + B_XBC + B_DA + B_PART + B_KV;  // u aliases g2
  const size_t persist = 2*2359296 + 2*2097152 + 40960;

  int C = 8;
  while (C > 1 && persist + (size_t)C * perC > ws_size) C >>= 1;
  const int nch = 8 / C;
  const int Mc  = C * LPB;

  char* p = (char*)d_ws;
  bf16*  win_h  = (bf16*)p;  p += 2359296;   // 2304x512
  bf16*  win_l  = (bf16*)p;  p += 2359296;
  bf16*  wout_h = (bf16*)p;  p += 2097152;   // 512x2048
  bf16*  wout_l = (bf16*)p;  p += 2097152;
  float* keff   = (float*)p; p += 40960;
  char*  arena  = p;                          // u hi/lo aliases g2 hi/lo
  bf16*  g2h    = (bf16*)arena;
  bf16*  g2l    = (bf16*)(arena + (size_t)C * B_G2);
  bf16*  u_h    = (bf16*)arena;
  bf16*  u_l    = (bf16*)(arena + (size_t)C * B_U);
  p = arena + (size_t)2 * C * B_G2;
  float* zx     = (float*)p; p += (size_t)C * B_ZX;   // also split-K partial arena
  float* xbc    = (float*)p; p += (size_t)C * B_XBC;
  float* dAb    = (float*)p; p += (size_t)C * B_DA;
  float* part   = (float*)p; p += (size_t)C * B_PART;
  float* KV     = (float*)p; p += (size_t)C * B_KV;

  k_split_win<<<4608, 256, 0, stream>>>(W_in, win_h, win_l);
  k_split    <<<1024, 256, 0, stream>>>(W_out, wout_h, wout_l);   // 512*2048/1024
  k_keff     <<<9, 128, 0, stream>>>(w33, w13x1, w31x1, w13x2, w31x2,
                                     w13bc1, w31bc1, w13bc2, w31bc2, keff);

  for (int ch = 0; ch < nch; ++ch) {
    const float* uc   = u + (size_t)ch * Mc * 512;
    float*       outc = (float*)d_out + (size_t)ch * Mc * 512;
    const int ntm = Mc / 128;

    k_split<<<Mc/2, 256, 0, stream>>>(uc, u_h, u_l);

    // GEMM1: zx = u @ W_in^T  (N padded to 2304, store-guard 2240), no split-K
    k_gemm3<<<ntm*18, 256, 0, stream>>>(u_h, u_l, 512, win_h, win_l, 512,
                                        zx, DPROJ, 512, DPROJ, 18, ntm*18, 0);

    // fused conv(z->g2[:,1024:]) + conv(xBC->xbc) + dA
    k_conv_all<<<dim3(Mc, 9), 256, 0, stream>>>(zx, keff, wz, a2, dt_bias, A_log,
                                                xbc, g2h, g2l, dAb);

    k_kv_part <<<dim3(32, C), 512, 0, stream>>>(xbc, dAb, part);
    k_kv_red  <<<dim3(64, C), 256, 0, stream>>>(part, KV);
    k_y_ln    <<<C*64, 256, 0, stream>>>(xbc, KV, Dp, ln_g, ln_b, sc, sh, a1, g2h, g2l);

    // GEMM2: split-K=4 into partials aliased on zx (dead now), then reduce into out
    float* kpart = zx;                       // 4 * Mc*512 f32 <= Mc*2240 f32
    const long cseg = (long)Mc * 512;
    k_gemm3<<<ntm*4*4, 256, 0, stream>>>(g2h, g2l, 2048, wout_h, wout_l, 2048,
                                         kpart, 512, 512, 512, 4, ntm*4, cseg);
    k_red4<<<Mc/2, 256, 0, stream>>>(kpart, cseg, outc);
  }
}

// Round 5
// 1136.216 us; speedup vs baseline: 1.3858x; 1.3254x over previous
//
#include <hip/hip_runtime.h>
#include <hip/hip_bf16.h>
#include <cstdint>
#include <cstddef>

// ---------------- problem constants ----------------
#define HDIM    64
#define WDIM    64
#define LPB     4096            // tokens per batch
#define DMODEL  512
#define DIN     1024
#define CONVD   1088
#define DPROJ   2240            // 2*DIN + 2*32 + 128
#define NHEADS  128
#define NCV     2112            // conv channels total (z 1024 + xBC 1088)

using bf16   = __bf16;
using bf16x8 = __attribute__((ext_vector_type(8))) __bf16;
using bf16x4 = __attribute__((ext_vector_type(4))) __bf16;
using f32x4  = __attribute__((ext_vector_type(4))) float;

__device__ __forceinline__ float siluf(float x) { return x / (1.f + __expf(-x)); }

// ---------------- hi/lo split prep ----------------
__global__ __launch_bounds__(256) void k_split(const float* __restrict__ in,
                                               bf16* __restrict__ h, bf16* __restrict__ l) {
  size_t i = ((size_t)blockIdx.x * 256 + threadIdx.x) * 4;
  f32x4 v = *(const f32x4*)(in + i);
  bf16x4 hh, ll;
  #pragma unroll
  for (int j = 0; j < 4; ++j) {
    hh[j] = (bf16)v[j];
    ll[j] = (bf16)(v[j] - (float)hh[j]);
  }
  *(bf16x4*)(h + i) = hh;
  *(bf16x4*)(l + i) = ll;
}

// W_in split with zero-pad to 2304 rows
__global__ __launch_bounds__(256) void k_split_win(const float* __restrict__ W,
                                                   bf16* __restrict__ h, bf16* __restrict__ l) {
  int i = blockIdx.x * 256 + threadIdx.x;    // over 2304*512
  int row = i >> 9, col = i & 511;
  float v = (row < DPROJ) ? W[row * 512 + col] : 0.f;
  bf16 hh = (bf16)v;
  h[i] = hh;
  l[i] = (bf16)(v - (float)hh);
}

// Effective per-channel 3x3 kernels, transposed: keffall[tap][channel c<2112].
// c<1024: z-conv weights (wz). c>=1024: collapsed interleave/separable kernels.
__global__ __launch_bounds__(256) void k_keff(const float* __restrict__ w33,
                       const float* __restrict__ w13x1, const float* __restrict__ w31x1,
                       const float* __restrict__ w13x2, const float* __restrict__ w31x2,
                       const float* __restrict__ w13bc1, const float* __restrict__ w31bc1,
                       const float* __restrict__ w13bc2, const float* __restrict__ w31bc2,
                       const float* __restrict__ wz,
                       float* __restrict__ keffall) {
  int j = blockIdx.x * 256 + threadIdx.x;
  if (j >= NCV) return;
  if (j < 1024) {
    #pragma unroll
    for (int tap = 0; tap < 9; ++tap) keffall[tap * NCV + j] = wz[j * 9 + tap];
    return;
  }
  int jj = j - 1024;
  float kh[3] = {0,0,0}, kw[3] = {0,0,0};
  bool dense = ((jj & 1) == 0);
  if (!dense) {
    int m = jj >> 2;                      // jj = 4m+1 or 4m+3
    if ((jj & 3) == 1) {
      if (m < 256) { for (int t=0;t<3;++t){ kh[t]=w31x1[m*3+t];  kw[t]=w13x1[m*3+t];  } }
      else { int q=m-256; for (int t=0;t<3;++t){ kh[t]=w31bc1[q*3+t]; kw[t]=w13bc1[q*3+t]; } }
    } else {
      if (m < 256) { for (int t=0;t<3;++t){ kh[t]=w31x2[m*3+t];  kw[t]=w13x2[m*3+t];  } }
      else { int q=m-256; for (int t=0;t<3;++t){ kh[t]=w31bc2[q*3+t]; kw[t]=w13bc2[q*3+t]; } }
    }
  }
  #pragma unroll
  for (int dh = 0; dh < 3; ++dh)
    #pragma unroll
    for (int dw = 0; dw < 3; ++dw) {
      float v = dense ? w33[(jj >> 1) * 9 + dh*3 + dw] : kh[dh] * kw[dw];
      keffall[(dh*3 + dw) * NCV + j] = v;
    }
}

// ---- split-bf16 MFMA GEMM with optional split-K (3-pass: AhBh + AhBl + AlBh) ----
__global__ __launch_bounds__(256) void k_gemm3(const bf16* __restrict__ Ah, const bf16* __restrict__ Al, int lda,
                                               const bf16* __restrict__ Bh, const bf16* __restrict__ Bl, int ldb,
                                               float* __restrict__ C, int ldc,
                                               int Kseg, int NW, int ntn, int ntmn, long Cseg) {
  __shared__ __align__(16) bf16 Ash[128 * 32];
  __shared__ __align__(16) bf16 Asl[128 * 32];
  __shared__ __align__(16) bf16 Bsh[128 * 32];
  __shared__ __align__(16) bf16 Bsl[128 * 32];

  // bijective chunked XCD swizzle (m204)
  int nwg = gridDim.x, bid = blockIdx.x;
  int q = nwg >> 3, r = nwg & 7;
  int xcd = bid & 7, loc = bid >> 3;
  int wg  = (xcd < r ? xcd * (q + 1) : r * (q + 1) + (xcd - r) * q) + loc;
  int kseg = wg / ntmn;
  int rem  = wg - kseg * ntmn;
  long m0 = (long)(rem / ntn) * 128;
  long n0 = (long)(rem % ntn) * 128;
  const int kbase = kseg * Kseg;

  const int tid  = threadIdx.x;
  const int w    = tid >> 6, lane = tid & 63;
  const int wr   = w >> 1, wc = w & 1;

  f32x4 acc[4][4];
  #pragma unroll
  for (int i = 0; i < 4; ++i)
    #pragma unroll
    for (int j = 0; j < 4; ++j) acc[i][j] = (f32x4){0.f,0.f,0.f,0.f};

  const int srow = w * 16 + (lane >> 2);   // staging row within 64-row half
  const int scol = (lane & 3) * 8;         // 8 bf16 = 16B per lane
  const long aoff = (m0 + srow) * (long)lda + scol + kbase;
  const long boff = (n0 + srow) * (long)ldb + scol + kbase;
  const int fr = lane & 15;
  const int kc = (lane >> 4) * 8;

  for (int k0 = 0; k0 < Kseg; k0 += 32) {
    #pragma unroll
    for (int i = 0; i < 2; ++i) {
      long ao = aoff + (long)i*64*lda + k0;
      long bo = boff + (long)i*64*ldb + k0;
      int ls = (i*4 + w) * 512;
      __builtin_amdgcn_global_load_lds((const __attribute__((address_space(1))) void*)(Ah + ao),
                                       (__attribute__((address_space(3))) void*)&Ash[ls], 16, 0, 0);
      __builtin_amdgcn_global_load_lds((const __attribute__((address_space(1))) void*)(Al + ao),
                                       (__attribute__((address_space(3))) void*)&Asl[ls], 16, 0, 0);
      __builtin_amdgcn_global_load_lds((const __attribute__((address_space(1))) void*)(Bh + bo),
                                       (__attribute__((address_space(3))) void*)&Bsh[ls], 16, 0, 0);
      __builtin_amdgcn_global_load_lds((const __attribute__((address_space(1))) void*)(Bl + bo),
                                       (__attribute__((address_space(3))) void*)&Bsl[ls], 16, 0, 0);
    }
    __syncthreads();
    bf16x8 ah[4], al[4], bh[4], bl[4];
    #pragma unroll
    for (int f = 0; f < 4; ++f) {
      int ar = (wr*64 + f*16 + fr) * 32 + kc;
      int br = (wc*64 + f*16 + fr) * 32 + kc;
      ah[f] = *(const bf16x8*)&Ash[ar];
      al[f] = *(const bf16x8*)&Asl[ar];
      bh[f] = *(const bf16x8*)&Bsh[br];
      bl[f] = *(const bf16x8*)&Bsl[br];
    }
    #pragma unroll
    for (int i = 0; i < 4; ++i)
      #pragma unroll
      for (int j = 0; j < 4; ++j) {
        acc[i][j] = __builtin_amdgcn_mfma_f32_16x16x32_bf16(ah[i], bh[j], acc[i][j], 0, 0, 0);
        acc[i][j] = __builtin_amdgcn_mfma_f32_16x16x32_bf16(ah[i], bl[j], acc[i][j], 0, 0, 0);
        acc[i][j] = __builtin_amdgcn_mfma_f32_16x16x32_bf16(al[i], bh[j], acc[i][j], 0, 0, 0);
      }
    __syncthreads();
  }

  float* Cb = C + (long)kseg * Cseg;
  const int cr = (lane >> 4) * 4;          // C/D: row=(lane>>4)*4+reg, col=lane&15
  const int cc = lane & 15;
  #pragma unroll
  for (int i = 0; i < 4; ++i) {
    long rbase = m0 + wr*64 + i*16 + cr;
    #pragma unroll
    for (int j = 0; j < 4; ++j) {
      int col = (int)n0 + wc*64 + j*16 + cc;
      if (col < NW) {
        float* cp = Cb + rbase * (long)ldc + col;
        #pragma unroll
        for (int r = 0; r < 4; ++r) cp[(long)r * ldc] = acc[i][j][r];
      }
    }
  }
}

// ---------------- split-K reduction: out = sum of 4 partials ----------------
__global__ __launch_bounds__(256) void k_red4(const float* __restrict__ part, long seg,
                                              float* __restrict__ out) {
  long i = ((long)blockIdx.x * 256 + threadIdx.x) * 4;
  f32x4 s0 = *(const f32x4*)(part + i);
  f32x4 s1 = *(const f32x4*)(part + seg + i);
  f32x4 s2 = *(const f32x4*)(part + 2*seg + i);
  f32x4 s3 = *(const f32x4*)(part + 3*seg + i);
  f32x4 o;
  #pragma unroll
  for (int j = 0; j < 4; ++j) o[j] = (s0[j] + s1[j]) + (s2[j] + s3[j]);
  *(f32x4*)(out + i) = o;
}

// ------ fused, x4-vectorized: dwconv z->g2 hi/lo | dwconv xBC->xbc | dt->dA ------
// One block per token (XCD-chunk-swizzled), 576 threads, 4 channels/thread.
__global__ __launch_bounds__(576) void k_conv_all(const float* __restrict__ zx,
                                                  const float* __restrict__ keffall,
                                                  const float* __restrict__ a2_p,
                                                  const float* __restrict__ dt_bias,
                                                  const float* __restrict__ A_log,
                                                  float* __restrict__ xbc,
                                                  bf16* __restrict__ g2h, bf16* __restrict__ g2l,
                                                  float* __restrict__ dAb) {
  int t = threadIdx.x;
  if (t >= 560) return;
  // XCD-chunk swizzle: each XCD owns a contiguous token range (gridDim.x % 8 == 0)
  int bid = blockIdx.x, qq = gridDim.x >> 3;
  int l = (bid & 7) * qq + (bid >> 3);
  int c = t * 4;
  int h = (l >> 6) & 63, wq = l & 63;
  long rowbase = (long)l * DPROJ;

  if (c < NCV) {
    f32x4 acc = (f32x4){0.f,0.f,0.f,0.f};
    #pragma unroll
    for (int dh = 0; dh < 3; ++dh) {
      int hh = h + dh - 1;
      if (hh < 0 || hh >= HDIM) continue;
      #pragma unroll
      for (int dw = 0; dw < 3; ++dw) {
        int ww = wq + dw - 1;
        if (ww < 0 || ww >= WDIM) continue;
        f32x4 v  = *(const f32x4*)&zx[rowbase + (long)((dh-1)*WDIM + (dw-1)) * DPROJ + c];
        f32x4 wt = *(const f32x4*)&keffall[(dh*3 + dw) * NCV + c];
        #pragma unroll
        for (int j = 0; j < 4; ++j) acc[j] = fmaf(v[j], wt[j], acc[j]);
      }
    }
    if (c < 1024) {
      float a2 = a2_p[0];
      bf16x4 h4, l4;
      #pragma unroll
      for (int j = 0; j < 4; ++j) {
        float vv = a2 * siluf(acc[j]);
        h4[j] = (bf16)vv;
        l4[j] = (bf16)(vv - (float)h4[j]);
      }
      long o = (long)l * 2048 + 1024 + c;
      *(bf16x4*)&g2h[o] = h4;
      *(bf16x4*)&g2l[o] = l4;
    } else {
      f32x4 o;
      #pragma unroll
      for (int j = 0; j < 4; ++j) o[j] = siluf(acc[j]);
      *(f32x4*)&xbc[(long)l * CONVD + (c - 1024)] = o;
    }
  } else {                                   // c in [2112, 2240): dt -> dA
    int hd = c - NCV;
    f32x4 x  = *(const f32x4*)&zx[rowbase + c];
    f32x4 db = *(const f32x4*)&dt_bias[hd];
    f32x4 al = *(const f32x4*)&A_log[hd];
    f32x4 o;
    #pragma unroll
    for (int j = 0; j < 4; ++j) {
      float xx = x[j] + db[j];
      float sp = (xx > 20.f) ? xx : log1pf(__expf(xx));
      o[j] = sp * __expf(al[j]);
    }
    *(f32x4*)&dAb[(long)l * 128 + hd] = o;
  }
}

// ---------------- KV partials over 128-token slices, then reduce ----------------
__global__ __launch_bounds__(512) void k_kv_part(const float* __restrict__ xbc,
                                                 const float* __restrict__ dA,
                                                 float* __restrict__ part) {
  int t = threadIdx.x;
  int m = t >> 3, p = t & 7;                 // m: head-pair 0..63, p: headdim 0..7
  int lc = blockIdx.x, b = blockIdx.y;       // b chunk-local
  float acc0[16], acc1[16];
  #pragma unroll
  for (int s = 0; s < 16; ++s) { acc0[s] = 0.f; acc1[s] = 0.f; }
  long lbase = (long)b * LPB + lc * 128;
  for (int li = 0; li < 128; ++li) {
    long row = lbase + li;
    const float* xr = xbc + row * CONVD;
    float a0 = dA[row * 128 + 2*m];
    float a1 = dA[row * 128 + 2*m + 1];
    float xv0 = xr[16*m + p]     * a0;   // head 2m   (group 0)
    float xv1 = xr[16*m + 8 + p] * a1;   // head 2m+1 (group 1)
    const float* Br = xr + DIN;          // Bm, uniform across threads
    #pragma unroll
    for (int s = 0; s < 16; ++s) {
      acc0[s] = fmaf(Br[s],      xv0, acc0[s]);
      acc1[s] = fmaf(Br[16 + s], xv1, acc1[s]);
    }
  }
  long base = ((long)(b*32 + lc)) * 16384 + (long)m * 256;
  #pragma unroll
  for (int s = 0; s < 16; ++s) {
    part[base + s*8 + p]       = acc0[s];
    part[base + 128 + s*8 + p] = acc1[s];
  }
}

__global__ __launch_bounds__(256) void k_kv_red(const float* __restrict__ part,
                                                float* __restrict__ KV) {
  int e = blockIdx.x * 256 + threadIdx.x;   // 16384 per b
  int b = blockIdx.y;
  float s = 0.f;
  #pragma unroll 4
  for (int lc = 0; lc < 32; ++lc) s += part[((long)(b*32 + lc)) * 16384 + e];
  KV[(long)b * 16384 + e] = s;
}

// --- y = Q*KV + x*Dp, LayerNorm, scale/shift, *alpha1 -> g2 cols [0,1024) hi/lo ---
// 32 tokens per block (2x parallelism vs r4).
__global__ __launch_bounds__(256) void k_y_ln(const float* __restrict__ xbc,
                                              const float* __restrict__ KV,
                                              const float* __restrict__ Dp,
                                              const float* __restrict__ ln_g,
                                              const float* __restrict__ ln_b,
                                              const float* __restrict__ sc_p,
                                              const float* __restrict__ sh_p,
                                              const float* __restrict__ a1_p,
                                              bf16* __restrict__ g2h, bf16* __restrict__ g2l) {
  __shared__ float Qs[32][32];
  __shared__ float red[8];
  int t = threadIdx.x;
  int hd = t >> 1, pb = (t & 1) * 4;
  int m = hd >> 1, g = hd & 1;
  int b = blockIdx.x >> 7;                  // chunk-local batch (128 groups/batch)
  long l0 = (long)b * LPB + (blockIdx.x & 127) * 32;

  f32x4 kv[16];
  #pragma unroll
  for (int s = 0; s < 16; ++s)
    kv[s] = *(const f32x4*)&KV[(long)b * 16384 + m*256 + g*128 + s*8 + pb];

  for (int i = t; i < 32*32; i += 256) {
    int tok = i >> 5, q = i & 31;
    Qs[tok][q] = xbc[(l0 + tok) * CONVD + 1056 + q];
  }
  int c0 = hd*8 + pb;
  f32x4 lg = *(const f32x4*)&ln_g[c0];
  f32x4 lb = *(const f32x4*)&ln_b[c0];
  float dpv = Dp[hd];
  float sc = sc_p[0], sh = sh_p[0], a1 = a1_p[0];
  int wv = t >> 6, lane = t & 63;
  __syncthreads();

  for (int tok = 0; tok < 32; ++tok) {
    long row = l0 + tok;
    f32x4 xv = *(const f32x4*)&xbc[row * CONVD + c0];
    f32x4 yv;
    #pragma unroll
    for (int j = 0; j < 4; ++j) yv[j] = xv[j] * dpv;
    #pragma unroll
    for (int s = 0; s < 16; ++s) {
      float qv = Qs[tok][g*16 + s];
      #pragma unroll
      for (int j = 0; j < 4; ++j) yv[j] = fmaf(qv, kv[s][j], yv[j]);
    }
    float s1 = yv[0] + yv[1] + yv[2] + yv[3];
    float s2 = yv[0]*yv[0] + yv[1]*yv[1] + yv[2]*yv[2] + yv[3]*yv[3];
    #pragma unroll
    for (int off = 1; off < 64; off <<= 1) {
      s1 += __shfl_xor(s1, off, 64);
      s2 += __shfl_xor(s2, off, 64);
    }
    if (lane == 0) { red[wv*2] = s1; red[wv*2 + 1] = s2; }
    __syncthreads();
    float S1 = red[0] + red[2] + red[4] + red[6];
    float S2 = red[1] + red[3] + red[5] + red[7];
    float mu   = S1 * (1.f/1024.f);
    float var  = S2 * (1.f/1024.f) - mu*mu;
    float rstd = rsqrtf(var + 1e-5f);
    bf16x4 h4, l4;
    #pragma unroll
    for (int j = 0; j < 4; ++j) {
      float yn = (yv[j] - mu) * rstd * lg[j] + lb[j];
      yn = a1 * (yn * sc + sh);
      h4[j] = (bf16)yn;
      l4[j] = (bf16)(yn - (float)h4[j]);
    }
    *(bf16x4*)&g2h[row * 2048 + c0] = h4;
    *(bf16x4*)&g2l[row * 2048 + c0] = l4;
    __syncthreads();   // protect red[] before next token
  }
}

// ---------------- host launcher ----------------
extern "C" void kernel_launch(void* const* d_in, const int* in_sizes, int n_in,
                              void* d_out, int out_size, void* d_ws, size_t ws_size,
                              hipStream_t stream) {
  const float* u       = (const float*)d_in[0];
  const float* W_in    = (const float*)d_in[3];
  const float* dt_bias = (const float*)d_in[4];
  const float* A_log   = (const float*)d_in[5];
  const float* Dp      = (const float*)d_in[6];
  const float* w33     = (const float*)d_in[7];
  const float* w13x1   = (const float*)d_in[8];
  const float* w31x1   = (const float*)d_in[9];
  const float* w13x2   = (const float*)d_in[10];
  const float* w31x2   = (const float*)d_in[11];
  const float* w13bc1  = (const float*)d_in[12];
  const float* w31bc1  = (const float*)d_in[13];
  const float* w13bc2  = (const float*)d_in[14];
  const float* w31bc2  = (const float*)d_in[15];
  const float* wz      = (const float*)d_in[16];
  const float* ln_g    = (const float*)d_in[17];
  const float* ln_b    = (const float*)d_in[18];
  const float* sc      = (const float*)d_in[19];
  const float* sh      = (const float*)d_in[20];
  const float* a1      = (const float*)d_in[21];
  const float* a2      = (const float*)d_in[22];
  const float* W_out   = (const float*)d_in[23];

  // per-batch buffer bytes (part lives in zx slack -> free)
  const size_t B_U    = 4194304;    // 4096x512 bf16 (each of hi/lo)
  const size_t B_G2   = 16777216;   // 4096x2048 bf16 (each of hi/lo)
  const size_t B_ZX   = 36700160;   // 4096x2240 f32 (later: split-K partials + kv partials)
  const size_t B_XBC  = 17825792;   // 4096x1088 f32
  const size_t B_DA   = 2097152;    // 4096x128 f32
  const size_t B_KV   = 65536;      // 16384 f32
  const size_t perC   = 2*B_G2 + B_ZX + B_XBC + B_DA + B_KV;  // u aliases g2
  const size_t persist = 2*2359296 + 2*2097152 + 76800;

  int C = 8;
  while (C > 1 && persist + (size_t)C * perC > ws_size) C >>= 1;
  const int nch = 8 / C;
  const int Mc  = C * LPB;

  char* p = (char*)d_ws;
  bf16*  win_h   = (bf16*)p;  p += 2359296;   // 2304x512
  bf16*  win_l   = (bf16*)p;  p += 2359296;
  bf16*  wout_h  = (bf16*)p;  p += 2097152;   // 512x2048
  bf16*  wout_l  = (bf16*)p;  p += 2097152;
  float* keffall = (float*)p; p += 76800;     // 9x2112 f32
  char*  arena   = p;                          // u hi/lo aliases g2 hi/lo
  bf16*  g2h     = (bf16*)arena;
  bf16*  g2l     = (bf16*)(arena + (size_t)C * B_G2);
  bf16*  u_h     = (bf16*)arena;
  bf16*  u_l     = (bf16*)(arena + (size_t)C * B_U);
  p = arena + (size_t)2 * C * B_G2;
  float* zx      = (float*)p; p += (size_t)C * B_ZX;
  float* xbc     = (float*)p; p += (size_t)C * B_XBC;
  float* dAb     = (float*)p; p += (size_t)C * B_DA;
  float* KV      = (float*)p; p += (size_t)C * B_KV;
  // kv partials in zx tail: zx[0 .. Mc*2048) is GEMM2 partial arena; tail is free.
  float* part    = zx + (size_t)Mc * 2048;    // needs Mc*128 f32 <= Mc*192 slack

  k_split_win<<<4608, 256, 0, stream>>>(W_in, win_h, win_l);
  k_split    <<<1024, 256, 0, stream>>>(W_out, wout_h, wout_l);   // 512*2048/1024
  k_keff     <<<9, 256, 0, stream>>>(w33, w13x1, w31x1, w13x2, w31x2,
                                     w13bc1, w31bc1, w13bc2, w31bc2, wz, keffall);

  for (int ch = 0; ch < nch; ++ch) {
    const float* uc   = u + (size_t)ch * Mc * 512;
    float*       outc = (float*)d_out + (size_t)ch * Mc * 512;
    const int ntm = Mc / 128;

    k_split<<<Mc/2, 256, 0, stream>>>(uc, u_h, u_l);

    // GEMM1: zx = u @ W_in^T  (N padded to 2304, store-guard 2240), no split-K
    k_gemm3<<<ntm*18, 256, 0, stream>>>(u_h, u_l, 512, win_h, win_l, 512,
                                        zx, DPROJ, 512, DPROJ, 18, ntm*18, 0);

    // fused vectorized conv(z->g2[:,1024:]) + conv(xBC->xbc) + dA
    k_conv_all<<<Mc, 576, 0, stream>>>(zx, keffall, a2, dt_bias, A_log,
                                       xbc, g2h, g2l, dAb);

    k_kv_part <<<dim3(32, C), 512, 0, stream>>>(xbc, dAb, part);
    k_kv_red  <<<dim3(64, C), 256, 0, stream>>>(part, KV);
    k_y_ln    <<<C*128, 256, 0, stream>>>(xbc, KV, Dp, ln_g, ln_b, sc, sh, a1, g2h, g2l);

    // GEMM2: split-K=4 into partials aliased on zx (dead now), then reduce into out
    float* kpart = zx;                       // 4 * Mc*512 f32 <= Mc*2048 f32 head
    const long cseg = (long)Mc * 512;
    k_gemm3<<<ntm*4*4, 256, 0, stream>>>(g2h, g2l, 2048, wout_h, wout_l, 2048,
                                         kpart, 512, 512, 512, 4, ntm*4, cseg);
    k_red4<<<Mc/2, 256, 0, stream>>>(kpart, cseg, outc);
  }
}

// Round 6
// 908.127 us; speedup vs baseline: 1.7338x; 1.2512x over previous
//
#include <hip/hip_runtime.h>
#include <hip/hip_bf16.h>
#include <cstdint>
#include <cstddef>

// ---------------- problem constants ----------------
#define HDIM    64
#define WDIM    64
#define LPB     4096            // tokens per batch
#define DMODEL  512
#define DIN     1024
#define CONVD   1088
#define DPROJ   2240            // 2*DIN + 2*32 + 128
#define NHEADS  128
#define NCV     2112            // conv channels total (z 1024 + xBC 1088)

using f16    = _Float16;
using f16x4  = __attribute__((ext_vector_type(4))) _Float16;
using f16x8  = __attribute__((ext_vector_type(8))) _Float16;
using f32x4  = __attribute__((ext_vector_type(4))) float;

__device__ __forceinline__ float siluf(float x) { return x / (1.f + __expf(-x)); }

// ---------------- f32 -> f16 conversion preps ----------------
__global__ __launch_bounds__(256) void k_cvt(const float* __restrict__ in, f16* __restrict__ out) {
  size_t i = ((size_t)blockIdx.x * 256 + threadIdx.x) * 4;
  f32x4 v = *(const f32x4*)(in + i);
  f16x4 o;
  #pragma unroll
  for (int j = 0; j < 4; ++j) o[j] = (f16)v[j];
  *(f16x4*)(out + i) = o;
}

// W_in with zero-pad to 2304 rows
__global__ __launch_bounds__(256) void k_cvt_win(const float* __restrict__ W, f16* __restrict__ out) {
  int i = blockIdx.x * 256 + threadIdx.x;    // over 2304*512
  int row = i >> 9, col = i & 511;
  float v = (row < DPROJ) ? W[row * 512 + col] : 0.f;
  out[i] = (f16)v;
}

// Effective per-channel 3x3 kernels, transposed: keffall[tap][channel c<2112].
// c<1024: z-conv weights (wz). c>=1024: collapsed interleave/separable kernels.
__global__ __launch_bounds__(256) void k_keff(const float* __restrict__ w33,
                       const float* __restrict__ w13x1, const float* __restrict__ w31x1,
                       const float* __restrict__ w13x2, const float* __restrict__ w31x2,
                       const float* __restrict__ w13bc1, const float* __restrict__ w31bc1,
                       const float* __restrict__ w13bc2, const float* __restrict__ w31bc2,
                       const float* __restrict__ wz,
                       float* __restrict__ keffall) {
  int j = blockIdx.x * 256 + threadIdx.x;
  if (j >= NCV) return;
  if (j < 1024) {
    #pragma unroll
    for (int tap = 0; tap < 9; ++tap) keffall[tap * NCV + j] = wz[j * 9 + tap];
    return;
  }
  int jj = j - 1024;
  float kh[3] = {0,0,0}, kw[3] = {0,0,0};
  bool dense = ((jj & 1) == 0);
  if (!dense) {
    int m = jj >> 2;                      // jj = 4m+1 or 4m+3
    if ((jj & 3) == 1) {
      if (m < 256) { for (int t=0;t<3;++t){ kh[t]=w31x1[m*3+t];  kw[t]=w13x1[m*3+t];  } }
      else { int q=m-256; for (int t=0;t<3;++t){ kh[t]=w31bc1[q*3+t]; kw[t]=w13bc1[q*3+t]; } }
    } else {
      if (m < 256) { for (int t=0;t<3;++t){ kh[t]=w31x2[m*3+t];  kw[t]=w13x2[m*3+t];  } }
      else { int q=m-256; for (int t=0;t<3;++t){ kh[t]=w31bc2[q*3+t]; kw[t]=w13bc2[q*3+t]; } }
    }
  }
  #pragma unroll
  for (int dh = 0; dh < 3; ++dh)
    #pragma unroll
    for (int dw = 0; dw < 3; ++dw) {
      float v = dense ? w33[(jj >> 1) * 9 + dh*3 + dw] : kh[dh] * kw[dw];
      keffall[(dh*3 + dw) * NCV + j] = v;
    }
}

// ---- single-pass fp16 MFMA GEMM with optional split-K; m97 structure, 128x128 tile ----
__global__ __launch_bounds__(256) void k_gemmf(const f16* __restrict__ A, int lda,
                                               const f16* __restrict__ Bm, int ldb,
                                               float* __restrict__ C, int ldc,
                                               int Kseg, int NW, int ntn, int ntmn, long Cseg) {
  __shared__ __align__(16) f16 As[128 * 32];
  __shared__ __align__(16) f16 Bs[128 * 32];

  // bijective chunked XCD swizzle (m204)
  int nwg = gridDim.x, bid = blockIdx.x;
  int q = nwg >> 3, r = nwg & 7;
  int xcd = bid & 7, loc = bid >> 3;
  int wg  = (xcd < r ? xcd * (q + 1) : r * (q + 1) + (xcd - r) * q) + loc;
  int kseg = wg / ntmn;
  int rem  = wg - kseg * ntmn;
  long m0 = (long)(rem / ntn) * 128;
  long n0 = (long)(rem % ntn) * 128;
  const int kbase = kseg * Kseg;

  const int tid  = threadIdx.x;
  const int w    = tid >> 6, lane = tid & 63;
  const int wr   = w >> 1, wc = w & 1;

  f32x4 acc[4][4];
  #pragma unroll
  for (int i = 0; i < 4; ++i)
    #pragma unroll
    for (int j = 0; j < 4; ++j) acc[i][j] = (f32x4){0.f,0.f,0.f,0.f};

  const int srow = w * 16 + (lane >> 2);   // staging row within 64-row half
  const int scol = (lane & 3) * 8;         // 8 f16 = 16B per lane
  const long aoff = (m0 + srow) * (long)lda + scol + kbase;
  const long boff = (n0 + srow) * (long)ldb + scol + kbase;
  const int fr = lane & 15;
  const int kc = (lane >> 4) * 8;

  for (int k0 = 0; k0 < Kseg; k0 += 32) {
    #pragma unroll
    for (int i = 0; i < 2; ++i) {
      long ao = aoff + (long)i*64*lda + k0;
      long bo = boff + (long)i*64*ldb + k0;
      int ls = (i*4 + w) * 512;
      __builtin_amdgcn_global_load_lds((const __attribute__((address_space(1))) void*)(A + ao),
                                       (__attribute__((address_space(3))) void*)&As[ls], 16, 0, 0);
      __builtin_amdgcn_global_load_lds((const __attribute__((address_space(1))) void*)(Bm + bo),
                                       (__attribute__((address_space(3))) void*)&Bs[ls], 16, 0, 0);
    }
    __syncthreads();
    f16x8 af[4], bf[4];
    #pragma unroll
    for (int f = 0; f < 4; ++f) {
      af[f] = *(const f16x8*)&As[(wr*64 + f*16 + fr) * 32 + kc];
      bf[f] = *(const f16x8*)&Bs[(wc*64 + f*16 + fr) * 32 + kc];
    }
    #pragma unroll
    for (int i = 0; i < 4; ++i)
      #pragma unroll
      for (int j = 0; j < 4; ++j)
        acc[i][j] = __builtin_amdgcn_mfma_f32_16x16x32_f16(af[i], bf[j], acc[i][j], 0, 0, 0);
    __syncthreads();
  }

  float* Cb = C + (long)kseg * Cseg;
  const int cr = (lane >> 4) * 4;          // C/D: row=(lane>>4)*4+reg, col=lane&15
  const int cc = lane & 15;
  #pragma unroll
  for (int i = 0; i < 4; ++i) {
    long rbase = m0 + wr*64 + i*16 + cr;
    #pragma unroll
    for (int j = 0; j < 4; ++j) {
      int col = (int)n0 + wc*64 + j*16 + cc;
      if (col < NW) {
        float* cp = Cb + rbase * (long)ldc + col;
        #pragma unroll
        for (int r = 0; r < 4; ++r) cp[(long)r * ldc] = acc[i][j][r];
      }
    }
  }
}

// ---------------- split-K reduction: out = sum of 4 partials ----------------
__global__ __launch_bounds__(256) void k_red4(const float* __restrict__ part, long seg,
                                              float* __restrict__ out) {
  long i = ((long)blockIdx.x * 256 + threadIdx.x) * 4;
  f32x4 s0 = *(const f32x4*)(part + i);
  f32x4 s1 = *(const f32x4*)(part + seg + i);
  f32x4 s2 = *(const f32x4*)(part + 2*seg + i);
  f32x4 s3 = *(const f32x4*)(part + 3*seg + i);
  f32x4 o;
  #pragma unroll
  for (int j = 0; j < 4; ++j) o[j] = (s0[j] + s1[j]) + (s2[j] + s3[j]);
  *(f32x4*)(out + i) = o;
}

// ------ fused, x4-vectorized: dwconv z->g2[:,1024:) f16 | dwconv xBC->xbc | dt->dA ------
// One block per token (XCD-chunk-swizzled), 576 threads, 4 channels/thread.
__global__ __launch_bounds__(576) void k_conv_all(const float* __restrict__ zx,
                                                  const float* __restrict__ keffall,
                                                  const float* __restrict__ a2_p,
                                                  const float* __restrict__ dt_bias,
                                                  const float* __restrict__ A_log,
                                                  float* __restrict__ xbc,
                                                  f16* __restrict__ g2,
                                                  float* __restrict__ dAb) {
  int t = threadIdx.x;
  if (t >= 560) return;
  // XCD-chunk swizzle: each XCD owns a contiguous token range (gridDim.x % 8 == 0)
  int bid = blockIdx.x, qq = gridDim.x >> 3;
  int l = (bid & 7) * qq + (bid >> 3);
  int c = t * 4;
  int h = (l >> 6) & 63, wq = l & 63;
  long rowbase = (long)l * DPROJ;

  if (c < NCV) {
    f32x4 acc = (f32x4){0.f,0.f,0.f,0.f};
    #pragma unroll
    for (int dh = 0; dh < 3; ++dh) {
      int hh = h + dh - 1;
      if (hh < 0 || hh >= HDIM) continue;
      #pragma unroll
      for (int dw = 0; dw < 3; ++dw) {
        int ww = wq + dw - 1;
        if (ww < 0 || ww >= WDIM) continue;
        f32x4 v  = *(const f32x4*)&zx[rowbase + (long)((dh-1)*WDIM + (dw-1)) * DPROJ + c];
        f32x4 wt = *(const f32x4*)&keffall[(dh*3 + dw) * NCV + c];
        #pragma unroll
        for (int j = 0; j < 4; ++j) acc[j] = fmaf(v[j], wt[j], acc[j]);
      }
    }
    if (c < 1024) {
      float a2 = a2_p[0];
      f16x4 o4;
      #pragma unroll
      for (int j = 0; j < 4; ++j) o4[j] = (f16)(a2 * siluf(acc[j]));
      *(f16x4*)&g2[(long)l * 2048 + 1024 + c] = o4;
    } else {
      f32x4 o;
      #pragma unroll
      for (int j = 0; j < 4; ++j) o[j] = siluf(acc[j]);
      *(f32x4*)&xbc[(long)l * CONVD + (c - 1024)] = o;
    }
  } else {                                   // c in [2112, 2240): dt -> dA
    int hd = c - NCV;
    f32x4 x  = *(const f32x4*)&zx[rowbase + c];
    f32x4 db = *(const f32x4*)&dt_bias[hd];
    f32x4 al = *(const f32x4*)&A_log[hd];
    f32x4 o;
    #pragma unroll
    for (int j = 0; j < 4; ++j) {
      float xx = x[j] + db[j];
      float sp = (xx > 20.f) ? xx : log1pf(__expf(xx));
      o[j] = sp * __expf(al[j]);
    }
    *(f32x4*)&dAb[(long)l * 128 + hd] = o;
  }
}

// ---------------- KV partials over 128-token slices, then reduce ----------------
__global__ __launch_bounds__(512) void k_kv_part(const float* __restrict__ xbc,
                                                 const float* __restrict__ dA,
                                                 float* __restrict__ part) {
  int t = threadIdx.x;
  int m = t >> 3, p = t & 7;                 // m: head-pair 0..63, p: headdim 0..7
  int lc = blockIdx.x, b = blockIdx.y;       // b chunk-local
  float acc0[16], acc1[16];
  #pragma unroll
  for (int s = 0; s < 16; ++s) { acc0[s] = 0.f; acc1[s] = 0.f; }
  long lbase = (long)b * LPB + lc * 128;
  for (int li = 0; li < 128; ++li) {
    long row = lbase + li;
    const float* xr = xbc + row * CONVD;
    float a0 = dA[row * 128 + 2*m];
    float a1 = dA[row * 128 + 2*m + 1];
    float xv0 = xr[16*m + p]     * a0;   // head 2m   (group 0)
    float xv1 = xr[16*m + 8 + p] * a1;   // head 2m+1 (group 1)
    const float* Br = xr + DIN;          // Bm, uniform across threads
    #pragma unroll
    for (int s = 0; s < 16; ++s) {
      acc0[s] = fmaf(Br[s],      xv0, acc0[s]);
      acc1[s] = fmaf(Br[16 + s], xv1, acc1[s]);
    }
  }
  long base = ((long)(b*32 + lc)) * 16384 + (long)m * 256;
  #pragma unroll
  for (int s = 0; s < 16; ++s) {
    part[base + s*8 + p]       = acc0[s];
    part[base + 128 + s*8 + p] = acc1[s];
  }
}

__global__ __launch_bounds__(256) void k_kv_red(const float* __restrict__ part,
                                                float* __restrict__ KV) {
  int e = blockIdx.x * 256 + threadIdx.x;   // 16384 per b
  int b = blockIdx.y;
  float s = 0.f;
  #pragma unroll 4
  for (int lc = 0; lc < 32; ++lc) s += part[((long)(b*32 + lc)) * 16384 + e];
  KV[(long)b * 16384 + e] = s;
}

// --- y = Q*KV + x*Dp, LayerNorm, scale/shift, *alpha1 -> g2 cols [0,1024) f16 ---
__global__ __launch_bounds__(256) void k_y_ln(const float* __restrict__ xbc,
                                              const float* __restrict__ KV,
                                              const float* __restrict__ Dp,
                                              const float* __restrict__ ln_g,
                                              const float* __restrict__ ln_b,
                                              const float* __restrict__ sc_p,
                                              const float* __restrict__ sh_p,
                                              const float* __restrict__ a1_p,
                                              f16* __restrict__ g2) {
  __shared__ float Qs[32][32];
  __shared__ float red[8];
  int t = threadIdx.x;
  int hd = t >> 1, pb = (t & 1) * 4;
  int m = hd >> 1, g = hd & 1;
  int b = blockIdx.x >> 7;                  // chunk-local batch (128 groups/batch)
  long l0 = (long)b * LPB + (blockIdx.x & 127) * 32;

  f32x4 kv[16];
  #pragma unroll
  for (int s = 0; s < 16; ++s)
    kv[s] = *(const f32x4*)&KV[(long)b * 16384 + m*256 + g*128 + s*8 + pb];

  for (int i = t; i < 32*32; i += 256) {
    int tok = i >> 5, q = i & 31;
    Qs[tok][q] = xbc[(l0 + tok) * CONVD + 1056 + q];
  }
  int c0 = hd*8 + pb;
  f32x4 lg = *(const f32x4*)&ln_g[c0];
  f32x4 lb = *(const f32x4*)&ln_b[c0];
  float dpv = Dp[hd];
  float sc = sc_p[0], sh = sh_p[0], a1 = a1_p[0];
  int wv = t >> 6, lane = t & 63;
  __syncthreads();

  for (int tok = 0; tok < 32; ++tok) {
    long row = l0 + tok;
    f32x4 xv = *(const f32x4*)&xbc[row * CONVD + c0];
    f32x4 yv;
    #pragma unroll
    for (int j = 0; j < 4; ++j) yv[j] = xv[j] * dpv;
    #pragma unroll
    for (int s = 0; s < 16; ++s) {
      float qv = Qs[tok][g*16 + s];
      #pragma unroll
      for (int j = 0; j < 4; ++j) yv[j] = fmaf(qv, kv[s][j], yv[j]);
    }
    float s1 = yv[0] + yv[1] + yv[2] + yv[3];
    float s2 = yv[0]*yv[0] + yv[1]*yv[1] + yv[2]*yv[2] + yv[3]*yv[3];
    #pragma unroll
    for (int off = 1; off < 64; off <<= 1) {
      s1 += __shfl_xor(s1, off, 64);
      s2 += __shfl_xor(s2, off, 64);
    }
    if (lane == 0) { red[wv*2] = s1; red[wv*2 + 1] = s2; }
    __syncthreads();
    float S1 = red[0] + red[2] + red[4] + red[6];
    float S2 = red[1] + red[3] + red[5] + red[7];
    float mu   = S1 * (1.f/1024.f);
    float var  = S2 * (1.f/1024.f) - mu*mu;
    float rstd = rsqrtf(var + 1e-5f);
    f16x4 o4;
    #pragma unroll
    for (int j = 0; j < 4; ++j) {
      float yn = (yv[j] - mu) * rstd * lg[j] + lb[j];
      o4[j] = (f16)(a1 * (yn * sc + sh));
    }
    *(f16x4*)&g2[row * 2048 + c0] = o4;
    __syncthreads();   // protect red[] before next token
  }
}

// ---------------- host launcher ----------------
extern "C" void kernel_launch(void* const* d_in, const int* in_sizes, int n_in,
                              void* d_out, int out_size, void* d_ws, size_t ws_size,
                              hipStream_t stream) {
  const float* u       = (const float*)d_in[0];
  const float* W_in    = (const float*)d_in[3];
  const float* dt_bias = (const float*)d_in[4];
  const float* A_log   = (const float*)d_in[5];
  const float* Dp      = (const float*)d_in[6];
  const float* w33     = (const float*)d_in[7];
  const float* w13x1   = (const float*)d_in[8];
  const float* w31x1   = (const float*)d_in[9];
  const float* w13x2   = (const float*)d_in[10];
  const float* w31x2   = (const float*)d_in[11];
  const float* w13bc1  = (const float*)d_in[12];
  const float* w31bc1  = (const float*)d_in[13];
  const float* w13bc2  = (const float*)d_in[14];
  const float* w31bc2  = (const float*)d_in[15];
  const float* wz      = (const float*)d_in[16];
  const float* ln_g    = (const float*)d_in[17];
  const float* ln_b    = (const float*)d_in[18];
  const float* sc      = (const float*)d_in[19];
  const float* sh      = (const float*)d_in[20];
  const float* a1      = (const float*)d_in[21];
  const float* a2      = (const float*)d_in[22];
  const float* W_out   = (const float*)d_in[23];

  // per-batch buffer bytes (u_f16 aliases g2; kv partials live in zx slack)
  const size_t B_G2   = 16777216;   // 4096x2048 f16
  const size_t B_ZX   = 36700160;   // 4096x2240 f32 (later: split-K partials + kv partials)
  const size_t B_XBC  = 17825792;   // 4096x1088 f32
  const size_t B_DA   = 2097152;    // 4096x128 f32
  const size_t B_KV   = 65536;      // 16384 f32
  const size_t perC   = B_G2 + B_ZX + B_XBC + B_DA + B_KV;
  const size_t persist = 2359296 + 2097152 + 76800;

  int C = 8;
  while (C > 1 && persist + (size_t)C * perC > ws_size) C >>= 1;
  const int nch = 8 / C;
  const int Mc  = C * LPB;

  char* p = (char*)d_ws;
  f16*   win_f   = (f16*)p;   p += 2359296;   // 2304x512
  f16*   wout_f  = (f16*)p;   p += 2097152;   // 512x2048
  float* keffall = (float*)p; p += 76800;     // 9x2112 f32
  char*  arena   = p;                          // u_f16 aliases g2
  f16*   g2      = (f16*)arena;
  f16*   u_f     = (f16*)arena;
  p = arena + (size_t)C * B_G2;
  float* zx      = (float*)p; p += (size_t)C * B_ZX;
  float* xbc     = (float*)p; p += (size_t)C * B_XBC;
  float* dAb     = (float*)p; p += (size_t)C * B_DA;
  float* KV      = (float*)p; p += (size_t)C * B_KV;
  // kv partials in zx tail: zx[0 .. Mc*2048) is GEMM2 partial arena; tail is free.
  float* part    = zx + (size_t)Mc * 2048;    // needs Mc*128 f32 <= Mc*192 slack

  k_cvt_win<<<4608, 256, 0, stream>>>(W_in, win_f);
  k_cvt    <<<1024, 256, 0, stream>>>(W_out, wout_f);   // 512*2048/1024
  k_keff   <<<9, 256, 0, stream>>>(w33, w13x1, w31x1, w13x2, w31x2,
                                   w13bc1, w31bc1, w13bc2, w31bc2, wz, keffall);

  for (int ch = 0; ch < nch; ++ch) {
    const float* uc   = u + (size_t)ch * Mc * 512;
    float*       outc = (float*)d_out + (size_t)ch * Mc * 512;
    const int ntm = Mc / 128;

    k_cvt<<<Mc/2, 256, 0, stream>>>(uc, u_f);   // Mc*512/1024 blocks

    // GEMM1: zx = u @ W_in^T  (N padded to 2304, store-guard 2240), no split-K
    k_gemmf<<<ntm*18, 256, 0, stream>>>(u_f, 512, win_f, 512,
                                        zx, DPROJ, 512, DPROJ, 18, ntm*18, 0);

    // fused vectorized conv(z->g2[:,1024:]) + conv(xBC->xbc) + dA
    k_conv_all<<<Mc, 576, 0, stream>>>(zx, keffall, a2, dt_bias, A_log,
                                       xbc, g2, dAb);

    k_kv_part <<<dim3(32, C), 512, 0, stream>>>(xbc, dAb, part);
    k_kv_red  <<<dim3(64, C), 256, 0, stream>>>(part, KV);
    k_y_ln    <<<C*128, 256, 0, stream>>>(xbc, KV, Dp, ln_g, ln_b, sc, sh, a1, g2);

    // GEMM2: split-K=4 into partials aliased on zx (dead now), then reduce into out
    float* kpart = zx;                       // 4 * Mc*512 f32 <= Mc*2048 f32 head
    const long cseg = (long)Mc * 512;
    k_gemmf<<<ntm*4*4, 256, 0, stream>>>(g2, 2048, wout_f, 2048,
                                         kpart, 512, 512, 512, 4, ntm*4, cseg);
    k_red4<<<Mc/2, 256, 0, stream>>>(kpart, cseg, outc);
  }
}

// Round 7
// 642.274 us; speedup vs baseline: 2.4515x; 1.4139x over previous
//
#include <hip/hip_runtime.h>
#include <hip/hip_bf16.h>
#include <cstdint>
#include <cstddef>

// ---------------- problem constants ----------------
#define HDIM    64
#define WDIM    64
#define LPB     4096            // tokens per batch
#define DMODEL  512
#define DIN     1024
#define CONVD   1088
#define DPROJ   2240            // 2*DIN + 2*32 + 128
#define NHEADS  128
#define NCV     2112            // conv channels total (z 1024 + xBC 1088)

using f16    = _Float16;
using f16x4  = __attribute__((ext_vector_type(4))) _Float16;
using f16x8  = __attribute__((ext_vector_type(8))) _Float16;
using f32x4  = __attribute__((ext_vector_type(4))) float;

__device__ __forceinline__ float siluf(float x) { return x / (1.f + __expf(-x)); }

// ---------------- f32 -> f16 conversion preps ----------------
__global__ __launch_bounds__(256) void k_cvt(const float* __restrict__ in, f16* __restrict__ out) {
  size_t i = ((size_t)blockIdx.x * 256 + threadIdx.x) * 4;
  f32x4 v = *(const f32x4*)(in + i);
  f16x4 o;
  #pragma unroll
  for (int j = 0; j < 4; ++j) o[j] = (f16)v[j];
  *(f16x4*)(out + i) = o;
}

// W_in with zero-pad to 2304 rows
__global__ __launch_bounds__(256) void k_cvt_win(const float* __restrict__ W, f16* __restrict__ out) {
  int i = blockIdx.x * 256 + threadIdx.x;    // over 2304*512
  int row = i >> 9, col = i & 511;
  float v = (row < DPROJ) ? W[row * 512 + col] : 0.f;
  out[i] = (f16)v;
}

// Effective per-channel 3x3 kernels, transposed f16: keffall[tap][channel c<2112].
__global__ __launch_bounds__(256) void k_keff(const float* __restrict__ w33,
                       const float* __restrict__ w13x1, const float* __restrict__ w31x1,
                       const float* __restrict__ w13x2, const float* __restrict__ w31x2,
                       const float* __restrict__ w13bc1, const float* __restrict__ w31bc1,
                       const float* __restrict__ w13bc2, const float* __restrict__ w31bc2,
                       const float* __restrict__ wz,
                       f16* __restrict__ keffall) {
  int j = blockIdx.x * 256 + threadIdx.x;
  if (j >= NCV) return;
  if (j < 1024) {
    #pragma unroll
    for (int tap = 0; tap < 9; ++tap) keffall[tap * NCV + j] = (f16)wz[j * 9 + tap];
    return;
  }
  int jj = j - 1024;
  float kh[3] = {0,0,0}, kw[3] = {0,0,0};
  bool dense = ((jj & 1) == 0);
  if (!dense) {
    int m = jj >> 2;                      // jj = 4m+1 or 4m+3
    if ((jj & 3) == 1) {
      if (m < 256) { for (int t=0;t<3;++t){ kh[t]=w31x1[m*3+t];  kw[t]=w13x1[m*3+t];  } }
      else { int q=m-256; for (int t=0;t<3;++t){ kh[t]=w31bc1[q*3+t]; kw[t]=w13bc1[q*3+t]; } }
    } else {
      if (m < 256) { for (int t=0;t<3;++t){ kh[t]=w31x2[m*3+t];  kw[t]=w13x2[m*3+t];  } }
      else { int q=m-256; for (int t=0;t<3;++t){ kh[t]=w31bc2[q*3+t]; kw[t]=w13bc2[q*3+t]; } }
    }
  }
  #pragma unroll
  for (int dh = 0; dh < 3; ++dh)
    #pragma unroll
    for (int dw = 0; dw < 3; ++dw) {
      float v = dense ? w33[(jj >> 1) * 9 + dh*3 + dw] : kh[dh] * kw[dw];
      keffall[(dh*3 + dw) * NCV + j] = (f16)v;
    }
}

// ---- single-pass fp16 MFMA GEMM with optional split-K; m97 structure, 128x128 tile ----
template<typename OutT>
__global__ __launch_bounds__(256) void k_gemmf(const f16* __restrict__ A, int lda,
                                               const f16* __restrict__ Bm, int ldb,
                                               OutT* __restrict__ C, int ldc,
                                               int Kseg, int NW, int ntn, int ntmn, long Cseg) {
  __shared__ __align__(16) f16 As[128 * 32];
  __shared__ __align__(16) f16 Bs[128 * 32];

  // bijective chunked XCD swizzle (m204)
  int nwg = gridDim.x, bid = blockIdx.x;
  int q = nwg >> 3, r = nwg & 7;
  int xcd = bid & 7, loc = bid >> 3;
  int wg  = (xcd < r ? xcd * (q + 1) : r * (q + 1) + (xcd - r) * q) + loc;
  int kseg = wg / ntmn;
  int rem  = wg - kseg * ntmn;
  long m0 = (long)(rem / ntn) * 128;
  long n0 = (long)(rem % ntn) * 128;
  const int kbase = kseg * Kseg;

  const int tid  = threadIdx.x;
  const int w    = tid >> 6, lane = tid & 63;
  const int wr   = w >> 1, wc = w & 1;

  f32x4 acc[4][4];
  #pragma unroll
  for (int i = 0; i < 4; ++i)
    #pragma unroll
    for (int j = 0; j < 4; ++j) acc[i][j] = (f32x4){0.f,0.f,0.f,0.f};

  const int srow = w * 16 + (lane >> 2);   // staging row within 64-row half
  const int scol = (lane & 3) * 8;         // 8 f16 = 16B per lane
  const long aoff = (m0 + srow) * (long)lda + scol + kbase;
  const long boff = (n0 + srow) * (long)ldb + scol + kbase;
  const int fr = lane & 15;
  const int kc = (lane >> 4) * 8;

  for (int k0 = 0; k0 < Kseg; k0 += 32) {
    #pragma unroll
    for (int i = 0; i < 2; ++i) {
      long ao = aoff + (long)i*64*lda + k0;
      long bo = boff + (long)i*64*ldb + k0;
      int ls = (i*4 + w) * 512;
      __builtin_amdgcn_global_load_lds((const __attribute__((address_space(1))) void*)(A + ao),
                                       (__attribute__((address_space(3))) void*)&As[ls], 16, 0, 0);
      __builtin_amdgcn_global_load_lds((const __attribute__((address_space(1))) void*)(Bm + bo),
                                       (__attribute__((address_space(3))) void*)&Bs[ls], 16, 0, 0);
    }
    __syncthreads();
    f16x8 af[4], bf[4];
    #pragma unroll
    for (int f = 0; f < 4; ++f) {
      af[f] = *(const f16x8*)&As[(wr*64 + f*16 + fr) * 32 + kc];
      bf[f] = *(const f16x8*)&Bs[(wc*64 + f*16 + fr) * 32 + kc];
    }
    #pragma unroll
    for (int i = 0; i < 4; ++i)
      #pragma unroll
      for (int j = 0; j < 4; ++j)
        acc[i][j] = __builtin_amdgcn_mfma_f32_16x16x32_f16(af[i], bf[j], acc[i][j], 0, 0, 0);
    __syncthreads();
  }

  OutT* Cb = C + (long)kseg * Cseg;
  const int cr = (lane >> 4) * 4;          // C/D: row=(lane>>4)*4+reg, col=lane&15
  const int cc = lane & 15;
  #pragma unroll
  for (int i = 0; i < 4; ++i) {
    long rbase = m0 + wr*64 + i*16 + cr;
    #pragma unroll
    for (int j = 0; j < 4; ++j) {
      int col = (int)n0 + wc*64 + j*16 + cc;
      if (col < NW) {
        OutT* cp = Cb + rbase * (long)ldc + col;
        #pragma unroll
        for (int r = 0; r < 4; ++r) cp[(long)r * ldc] = (OutT)acc[i][j][r];
      }
    }
  }
}

// ---------------- split-K reduction: out = sum of 2 partials ----------------
__global__ __launch_bounds__(256) void k_red2(const float* __restrict__ part, long seg,
                                              float* __restrict__ out) {
  long i = ((long)blockIdx.x * 256 + threadIdx.x) * 4;
  f32x4 s0 = *(const f32x4*)(part + i);
  f32x4 s1 = *(const f32x4*)(part + seg + i);
  f32x4 o;
  #pragma unroll
  for (int j = 0; j < 4; ++j) o[j] = s0[j] + s1[j];
  *(f32x4*)(out + i) = o;
}

// ------ fused, x8-vectorized f16: dwconv z->g2[:,1024:) | dwconv xBC->xbc | dt->dA ------
// One block per token (XCD-chunk-swizzled), 320 threads (280 active), 8 channels/thread.
__global__ __launch_bounds__(320) void k_conv_all(const f16* __restrict__ zx,
                                                  const f16* __restrict__ keffall,
                                                  const float* __restrict__ a2_p,
                                                  const float* __restrict__ dt_bias,
                                                  const float* __restrict__ A_log,
                                                  f16* __restrict__ xbc,
                                                  f16* __restrict__ g2,
                                                  float* __restrict__ dAb) {
  int t = threadIdx.x;
  // XCD-chunk swizzle: each XCD owns a contiguous token range (gridDim.x % 8 == 0)
  int bid = blockIdx.x, qq = gridDim.x >> 3;
  int l = (bid & 7) * qq + (bid >> 3);
  int h = (l >> 6) & 63, wq = l & 63;
  long rowbase = (long)l * DPROJ;

  if (t < 264) {                             // conv: 8 channels per thread
    int c = t * 8;
    float acc[8] = {0,0,0,0,0,0,0,0};
    #pragma unroll
    for (int dh = 0; dh < 3; ++dh) {
      int hh = h + dh - 1;
      if (hh < 0 || hh >= HDIM) continue;
      #pragma unroll
      for (int dw = 0; dw < 3; ++dw) {
        int ww = wq + dw - 1;
        if (ww < 0 || ww >= WDIM) continue;
        f16x8 v  = *(const f16x8*)&zx[rowbase + (long)((dh-1)*WDIM + (dw-1)) * DPROJ + c];
        f16x8 wt = *(const f16x8*)&keffall[(dh*3 + dw) * NCV + c];
        #pragma unroll
        for (int j = 0; j < 8; ++j) acc[j] = fmaf((float)v[j], (float)wt[j], acc[j]);
      }
    }
    f16x8 o8;
    if (c < 1024) {
      float a2 = a2_p[0];
      #pragma unroll
      for (int j = 0; j < 8; ++j) o8[j] = (f16)(a2 * siluf(acc[j]));
      *(f16x8*)&g2[(long)l * 2048 + 1024 + c] = o8;
    } else {
      #pragma unroll
      for (int j = 0; j < 8; ++j) o8[j] = (f16)siluf(acc[j]);
      *(f16x8*)&xbc[(long)l * CONVD + (c - 1024)] = o8;
    }
  } else if (t < 280) {                      // dt -> dA, 8 heads per thread
    int hd = (t - 264) * 8;
    f16x8 x = *(const f16x8*)&zx[rowbase + NCV + hd];
    f32x4 o0, o1;
    #pragma unroll
    for (int j = 0; j < 8; ++j) {
      float xx = (float)x[j] + dt_bias[hd + j];
      float sp = (xx > 20.f) ? xx : log1pf(__expf(xx));
      float dv = sp * __expf(A_log[hd + j]);
      if (j < 4) o0[j] = dv; else o1[j-4] = dv;
    }
    *(f32x4*)&dAb[(long)l * 128 + hd]     = o0;
    *(f32x4*)&dAb[(long)l * 128 + hd + 4] = o1;
  }
}

// ---------------- KV partials over 32-token slices, then reduce ----------------
__global__ __launch_bounds__(512) void k_kv_part(const f16* __restrict__ xbc,
                                                 const float* __restrict__ dA,
                                                 float* __restrict__ part) {
  int t = threadIdx.x;
  int m = t >> 3, p = t & 7;                 // m: head-pair 0..63, p: headdim 0..7
  int lc = blockIdx.x, b = blockIdx.y;       // lc: 0..127 (32 tokens each), b chunk-local
  float acc0[16], acc1[16];
  #pragma unroll
  for (int s = 0; s < 16; ++s) { acc0[s] = 0.f; acc1[s] = 0.f; }
  long lbase = (long)b * LPB + lc * 32;
  for (int li = 0; li < 32; ++li) {
    long row = lbase + li;
    const f16* xr = xbc + row * CONVD;
    float a0 = dA[row * 128 + 2*m];
    float a1 = dA[row * 128 + 2*m + 1];
    float xv0 = (float)xr[16*m + p]     * a0;   // head 2m   (group 0)
    float xv1 = (float)xr[16*m + 8 + p] * a1;   // head 2m+1 (group 1)
    const f16* Br = xr + DIN;                   // Bm, uniform across threads
    #pragma unroll
    for (int s = 0; s < 16; ++s) {
      acc0[s] = fmaf((float)Br[s],      xv0, acc0[s]);
      acc1[s] = fmaf((float)Br[16 + s], xv1, acc1[s]);
    }
  }
  long base = ((long)(b*128 + lc)) * 16384 + (long)m * 256;
  #pragma unroll
  for (int s = 0; s < 16; ++s) {
    part[base + s*8 + p]       = acc0[s];
    part[base + 128 + s*8 + p] = acc1[s];
  }
}

__global__ __launch_bounds__(256) void k_kv_red(const float* __restrict__ part,
                                                float* __restrict__ KV) {
  int e = blockIdx.x * 256 + threadIdx.x;   // 16384 per b
  int b = blockIdx.y;
  float s = 0.f;
  #pragma unroll 4
  for (int lc = 0; lc < 128; ++lc) s += part[((long)(b*128 + lc)) * 16384 + e];
  KV[(long)b * 16384 + e] = s;
}

// --- y = Q*KV + x*Dp, LayerNorm, scale/shift, *alpha1 -> g2 cols [0,1024) f16 ---
__global__ __launch_bounds__(256) void k_y_ln(const f16* __restrict__ xbc,
                                              const float* __restrict__ KV,
                                              const float* __restrict__ Dp,
                                              const float* __restrict__ ln_g,
                                              const float* __restrict__ ln_b,
                                              const float* __restrict__ sc_p,
                                              const float* __restrict__ sh_p,
                                              const float* __restrict__ a1_p,
                                              f16* __restrict__ g2) {
  __shared__ float Qs[32][32];
  __shared__ float red[8];
  int t = threadIdx.x;
  int hd = t >> 1, pb = (t & 1) * 4;
  int m = hd >> 1, g = hd & 1;
  int b = blockIdx.x >> 7;                  // chunk-local batch (128 groups/batch)
  long l0 = (long)b * LPB + (blockIdx.x & 127) * 32;

  f32x4 kv[16];
  #pragma unroll
  for (int s = 0; s < 16; ++s)
    kv[s] = *(const f32x4*)&KV[(long)b * 16384 + m*256 + g*128 + s*8 + pb];

  for (int i = t; i < 32*32; i += 256) {
    int tok = i >> 5, q = i & 31;
    Qs[tok][q] = (float)xbc[(l0 + tok) * CONVD + 1056 + q];
  }
  int c0 = hd*8 + pb;
  f32x4 lg = *(const f32x4*)&ln_g[c0];
  f32x4 lb = *(const f32x4*)&ln_b[c0];
  float dpv = Dp[hd];
  float sc = sc_p[0], sh = sh_p[0], a1 = a1_p[0];
  int wv = t >> 6, lane = t & 63;
  __syncthreads();

  for (int tok = 0; tok < 32; ++tok) {
    long row = l0 + tok;
    f16x4 xr4 = *(const f16x4*)&xbc[row * CONVD + c0];
    f32x4 yv;
    #pragma unroll
    for (int j = 0; j < 4; ++j) yv[j] = (float)xr4[j] * dpv;
    #pragma unroll
    for (int s = 0; s < 16; ++s) {
      float qv = Qs[tok][g*16 + s];
      #pragma unroll
      for (int j = 0; j < 4; ++j) yv[j] = fmaf(qv, kv[s][j], yv[j]);
    }
    float s1 = yv[0] + yv[1] + yv[2] + yv[3];
    float s2 = yv[0]*yv[0] + yv[1]*yv[1] + yv[2]*yv[2] + yv[3]*yv[3];
    #pragma unroll
    for (int off = 1; off < 64; off <<= 1) {
      s1 += __shfl_xor(s1, off, 64);
      s2 += __shfl_xor(s2, off, 64);
    }
    if (lane == 0) { red[wv*2] = s1; red[wv*2 + 1] = s2; }
    __syncthreads();
    float S1 = red[0] + red[2] + red[4] + red[6];
    float S2 = red[1] + red[3] + red[5] + red[7];
    float mu   = S1 * (1.f/1024.f);
    float var  = S2 * (1.f/1024.f) - mu*mu;
    float rstd = rsqrtf(var + 1e-5f);
    f16x4 o4;
    #pragma unroll
    for (int j = 0; j < 4; ++j) {
      float yn = (yv[j] - mu) * rstd * lg[j] + lb[j];
      o4[j] = (f16)(a1 * (yn * sc + sh));
    }
    *(f16x4*)&g2[row * 2048 + c0] = o4;
    __syncthreads();   // protect red[] before next token
  }
}

// ---------------- host launcher ----------------
extern "C" void kernel_launch(void* const* d_in, const int* in_sizes, int n_in,
                              void* d_out, int out_size, void* d_ws, size_t ws_size,
                              hipStream_t stream) {
  const float* u       = (const float*)d_in[0];
  const float* W_in    = (const float*)d_in[3];
  const float* dt_bias = (const float*)d_in[4];
  const float* A_log   = (const float*)d_in[5];
  const float* Dp      = (const float*)d_in[6];
  const float* w33     = (const float*)d_in[7];
  const float* w13x1   = (const float*)d_in[8];
  const float* w31x1   = (const float*)d_in[9];
  const float* w13x2   = (const float*)d_in[10];
  const float* w31x2   = (const float*)d_in[11];
  const float* w13bc1  = (const float*)d_in[12];
  const float* w31bc1  = (const float*)d_in[13];
  const float* w13bc2  = (const float*)d_in[14];
  const float* w31bc2  = (const float*)d_in[15];
  const float* wz      = (const float*)d_in[16];
  const float* ln_g    = (const float*)d_in[17];
  const float* ln_b    = (const float*)d_in[18];
  const float* sc      = (const float*)d_in[19];
  const float* sh      = (const float*)d_in[20];
  const float* a1      = (const float*)d_in[21];
  const float* a2      = (const float*)d_in[22];
  const float* W_out   = (const float*)d_in[23];

  // per-batch buffer bytes (u_f16 aliases g2; kv partials + gemm2 partials live in zx)
  const size_t B_G2   = 16777216;   // 4096x2048 f16
  const size_t B_ZX   = 18350080;   // 4096x2240 f16 (dead after conv; reused as partial arenas)
  const size_t B_XBC  = 8912896;    // 4096x1088 f16
  const size_t B_DA   = 2097152;    // 4096x128 f32
  const size_t B_KV   = 65536;      // 16384 f32
  const size_t perC   = B_G2 + B_ZX + B_XBC + B_DA + B_KV;   // 46.2 MB
  const size_t persist = 2359296 + 2097152 + 38912;

  int C = 8;
  while (C > 1 && persist + (size_t)C * perC > ws_size) C >>= 1;
  const int nch = 8 / C;
  const int Mc  = C * LPB;

  char* p = (char*)d_ws;
  f16*   win_f   = (f16*)p;   p += 2359296;   // 2304x512
  f16*   wout_f  = (f16*)p;   p += 2097152;   // 512x2048
  f16*   keffall = (f16*)p;   p += 38912;     // 9x2112 f16 (padded)
  char*  arena   = p;                          // u_f16 aliases g2
  f16*   g2      = (f16*)arena;
  f16*   u_f     = (f16*)arena;
  p = arena + (size_t)C * B_G2;
  f16*   zx      = (f16*)p;   p += (size_t)C * B_ZX;
  f16*   xbc     = (f16*)p;   p += (size_t)C * B_XBC;
  float* dAb     = (float*)p; p += (size_t)C * B_DA;
  float* KV      = (float*)p; p += (size_t)C * B_KV;
  // zx arena reuse after conv: kv partials (C*128*16384 f32 = C*8.4MB <= C*18.35MB),
  // then GEMM2 split-K partials (2 * Mc*512 f32 = Mc*4096B <= Mc*4480B).
  float* part  = (float*)zx;
  float* kpart = (float*)zx;

  k_cvt_win<<<4608, 256, 0, stream>>>(W_in, win_f);
  k_cvt    <<<1024, 256, 0, stream>>>(W_out, wout_f);   // 512*2048/1024
  k_keff   <<<9, 256, 0, stream>>>(w33, w13x1, w31x1, w13x2, w31x2,
                                   w13bc1, w31bc1, w13bc2, w31bc2, wz, keffall);

  for (int ch = 0; ch < nch; ++ch) {
    const float* uc   = u + (size_t)ch * Mc * 512;
    float*       outc = (float*)d_out + (size_t)ch * Mc * 512;
    const int ntm = Mc / 128;

    k_cvt<<<Mc/2, 256, 0, stream>>>(uc, u_f);   // Mc*512/1024 blocks

    // GEMM1: zx(f16) = u @ W_in^T  (N padded to 2304, store-guard 2240)
    k_gemmf<f16><<<ntm*18, 256, 0, stream>>>(u_f, 512, win_f, 512,
                                             zx, DPROJ, 512, DPROJ, 18, ntm*18, 0);

    // fused f16 conv(z->g2[:,1024:]) + conv(xBC->xbc) + dA
    k_conv_all<<<Mc, 320, 0, stream>>>(zx, keffall, a2, dt_bias, A_log,
                                       xbc, g2, dAb);

    // attention KV (zx arena now dead -> partials live there)
    k_kv_part <<<dim3(128, C), 512, 0, stream>>>(xbc, dAb, part);
    k_kv_red  <<<dim3(64, C), 256, 0, stream>>>(part, KV);
    k_y_ln    <<<C*128, 256, 0, stream>>>(xbc, KV, Dp, ln_g, ln_b, sc, sh, a1, g2);

    // GEMM2: split-K=2 partials in zx arena, then reduce into out
    const long cseg = (long)Mc * 512;
    k_gemmf<float><<<ntm*4*2, 256, 0, stream>>>(g2, 2048, wout_f, 2048,
                                                kpart, 512, 1024, 512, 4, ntm*4, cseg);
    k_red2<<<Mc/2, 256, 0, stream>>>(kpart, cseg, outc);
  }
}

// Round 8
// 634.744 us; speedup vs baseline: 2.4806x; 1.0119x over previous
//
#include <hip/hip_runtime.h>
#include <hip/hip_bf16.h>
#include <cstdint>
#include <cstddef>

// ---------------- problem constants ----------------
#define HDIM    64
#define WDIM    64
#define LPB     4096            // tokens per batch
#define DMODEL  512
#define DIN     1024
#define CONVD   1088
#define DPROJ   2240            // 2*DIN + 2*32 + 128
#define NHEADS  128
#define NCV     2112            // conv channels total (z 1024 + xBC 1088)

using f16    = _Float16;
using f16x4  = __attribute__((ext_vector_type(4))) _Float16;
using f16x8  = __attribute__((ext_vector_type(8))) _Float16;
using f32x4  = __attribute__((ext_vector_type(4))) float;

__device__ __forceinline__ float siluf(float x) { return x / (1.f + __expf(-x)); }

// acc += f16lo(a) * f16lo(b)  /  acc += f16hi(a) * f16hi(b)   (f32 accumulate, 1 instr)
__device__ __forceinline__ void fma_mix_lo(float& acc, unsigned a, unsigned b) {
  asm("v_fma_mix_f32 %0, %1, %2, %0 op_sel_hi:[1,1,0]" : "+v"(acc) : "v"(a), "v"(b));
}
__device__ __forceinline__ void fma_mix_hi(float& acc, unsigned a, unsigned b) {
  asm("v_fma_mix_f32 %0, %1, %2, %0 op_sel:[1,1,0] op_sel_hi:[1,1,0]" : "+v"(acc) : "v"(a), "v"(b));
}

// ---------------- f32 -> f16 conversion preps ----------------
__global__ __launch_bounds__(256) void k_cvt(const float* __restrict__ in, f16* __restrict__ out) {
  size_t i = ((size_t)blockIdx.x * 256 + threadIdx.x) * 4;
  f32x4 v = *(const f32x4*)(in + i);
  f16x4 o;
  #pragma unroll
  for (int j = 0; j < 4; ++j) o[j] = (f16)v[j];
  *(f16x4*)(out + i) = o;
}

// W_in with zero-pad to 2304 rows
__global__ __launch_bounds__(256) void k_cvt_win(const float* __restrict__ W, f16* __restrict__ out) {
  int i = blockIdx.x * 256 + threadIdx.x;    // over 2304*512
  int row = i >> 9, col = i & 511;
  float v = (row < DPROJ) ? W[row * 512 + col] : 0.f;
  out[i] = (f16)v;
}

// Effective per-channel 3x3 kernels, transposed f16: keffall[tap][channel c<2112].
__global__ __launch_bounds__(256) void k_keff(const float* __restrict__ w33,
                       const float* __restrict__ w13x1, const float* __restrict__ w31x1,
                       const float* __restrict__ w13x2, const float* __restrict__ w31x2,
                       const float* __restrict__ w13bc1, const float* __restrict__ w31bc1,
                       const float* __restrict__ w13bc2, const float* __restrict__ w31bc2,
                       const float* __restrict__ wz,
                       f16* __restrict__ keffall) {
  int j = blockIdx.x * 256 + threadIdx.x;
  if (j >= NCV) return;
  if (j < 1024) {
    #pragma unroll
    for (int tap = 0; tap < 9; ++tap) keffall[tap * NCV + j] = (f16)wz[j * 9 + tap];
    return;
  }
  int jj = j - 1024;
  float kh[3] = {0,0,0}, kw[3] = {0,0,0};
  bool dense = ((jj & 1) == 0);
  if (!dense) {
    int m = jj >> 2;                      // jj = 4m+1 or 4m+3
    if ((jj & 3) == 1) {
      if (m < 256) { for (int t=0;t<3;++t){ kh[t]=w31x1[m*3+t];  kw[t]=w13x1[m*3+t];  } }
      else { int q=m-256; for (int t=0;t<3;++t){ kh[t]=w31bc1[q*3+t]; kw[t]=w13bc1[q*3+t]; } }
    } else {
      if (m < 256) { for (int t=0;t<3;++t){ kh[t]=w31x2[m*3+t];  kw[t]=w13x2[m*3+t];  } }
      else { int q=m-256; for (int t=0;t<3;++t){ kh[t]=w31bc2[q*3+t]; kw[t]=w13bc2[q*3+t]; } }
    }
  }
  #pragma unroll
  for (int dh = 0; dh < 3; ++dh)
    #pragma unroll
    for (int dw = 0; dw < 3; ++dw) {
      float v = dense ? w33[(jj >> 1) * 9 + dh*3 + dw] : kh[dh] * kw[dw];
      keffall[(dh*3 + dw) * NCV + j] = (f16)v;
    }
}

// ---- single-pass fp16 MFMA GEMM with optional split-K; m97 structure, 128x128 tile ----
template<typename OutT>
__global__ __launch_bounds__(256) void k_gemmf(const f16* __restrict__ A, int lda,
                                               const f16* __restrict__ Bm, int ldb,
                                               OutT* __restrict__ C, int ldc,
                                               int Kseg, int NW, int ntn, int ntmn, long Cseg) {
  __shared__ __align__(16) f16 As[128 * 32];
  __shared__ __align__(16) f16 Bs[128 * 32];

  // bijective chunked XCD swizzle (m204)
  int nwg = gridDim.x, bid = blockIdx.x;
  int q = nwg >> 3, r = nwg & 7;
  int xcd = bid & 7, loc = bid >> 3;
  int wg  = (xcd < r ? xcd * (q + 1) : r * (q + 1) + (xcd - r) * q) + loc;
  int kseg = wg / ntmn;
  int rem  = wg - kseg * ntmn;
  long m0 = (long)(rem / ntn) * 128;
  long n0 = (long)(rem % ntn) * 128;
  const int kbase = kseg * Kseg;

  const int tid  = threadIdx.x;
  const int w    = tid >> 6, lane = tid & 63;
  const int wr   = w >> 1, wc = w & 1;

  f32x4 acc[4][4];
  #pragma unroll
  for (int i = 0; i < 4; ++i)
    #pragma unroll
    for (int j = 0; j < 4; ++j) acc[i][j] = (f32x4){0.f,0.f,0.f,0.f};

  const int srow = w * 16 + (lane >> 2);   // staging row within 64-row half
  const int scol = (lane & 3) * 8;         // 8 f16 = 16B per lane
  const long aoff = (m0 + srow) * (long)lda + scol + kbase;
  const long boff = (n0 + srow) * (long)ldb + scol + kbase;
  const int fr = lane & 15;
  const int kc = (lane >> 4) * 8;

  for (int k0 = 0; k0 < Kseg; k0 += 32) {
    #pragma unroll
    for (int i = 0; i < 2; ++i) {
      long ao = aoff + (long)i*64*lda + k0;
      long bo = boff + (long)i*64*ldb + k0;
      int ls = (i*4 + w) * 512;
      __builtin_amdgcn_global_load_lds((const __attribute__((address_space(1))) void*)(A + ao),
                                       (__attribute__((address_space(3))) void*)&As[ls], 16, 0, 0);
      __builtin_amdgcn_global_load_lds((const __attribute__((address_space(1))) void*)(Bm + bo),
                                       (__attribute__((address_space(3))) void*)&Bs[ls], 16, 0, 0);
    }
    __syncthreads();
    f16x8 af[4], bf[4];
    #pragma unroll
    for (int f = 0; f < 4; ++f) {
      af[f] = *(const f16x8*)&As[(wr*64 + f*16 + fr) * 32 + kc];
      bf[f] = *(const f16x8*)&Bs[(wc*64 + f*16 + fr) * 32 + kc];
    }
    #pragma unroll
    for (int i = 0; i < 4; ++i)
      #pragma unroll
      for (int j = 0; j < 4; ++j)
        acc[i][j] = __builtin_amdgcn_mfma_f32_16x16x32_f16(af[i], bf[j], acc[i][j], 0, 0, 0);
    __syncthreads();
  }

  OutT* Cb = C + (long)kseg * Cseg;
  const int cr = (lane >> 4) * 4;          // C/D: row=(lane>>4)*4+reg, col=lane&15
  const int cc = lane & 15;
  #pragma unroll
  for (int i = 0; i < 4; ++i) {
    long rbase = m0 + wr*64 + i*16 + cr;
    #pragma unroll
    for (int j = 0; j < 4; ++j) {
      int col = (int)n0 + wc*64 + j*16 + cc;
      if (col < NW) {
        OutT* cp = Cb + rbase * (long)ldc + col;
        #pragma unroll
        for (int r = 0; r < 4; ++r) cp[(long)r * ldc] = (OutT)acc[i][j][r];
      }
    }
  }
}

// ---------------- split-K reduction: out = sum of 2 partials ----------------
__global__ __launch_bounds__(256) void k_red2(const float* __restrict__ part, long seg,
                                              float* __restrict__ out) {
  long i = ((long)blockIdx.x * 256 + threadIdx.x) * 4;
  f32x4 s0 = *(const f32x4*)(part + i);
  f32x4 s1 = *(const f32x4*)(part + seg + i);
  f32x4 o;
  #pragma unroll
  for (int j = 0; j < 4; ++j) o[j] = s0[j] + s1[j];
  *(f32x4*)(out + i) = o;
}

// ------ fused f16 conv via v_fma_mix_f32: z->g2[:,1024:) | xBC->xbc | dt->dA ------
// One block per token (XCD-chunk-swizzled), 320 threads (280 active), 8 channels/thread.
__global__ __launch_bounds__(320) void k_conv_all(const f16* __restrict__ zx,
                                                  const f16* __restrict__ keffall,
                                                  const float* __restrict__ a2_p,
                                                  const float* __restrict__ dt_bias,
                                                  const float* __restrict__ A_log,
                                                  f16* __restrict__ xbc,
                                                  f16* __restrict__ g2,
                                                  float* __restrict__ dAb) {
  int t = threadIdx.x;
  // XCD-chunk swizzle: each XCD owns a contiguous token range (gridDim.x % 8 == 0)
  int bid = blockIdx.x, qq = gridDim.x >> 3;
  int l = (bid & 7) * qq + (bid >> 3);
  int h = (l >> 6) & 63, wq = l & 63;
  long rowbase = (long)l * DPROJ;

  if (t < 264) {                             // conv: 8 channels per thread
    int c = t * 8;
    float acc[8] = {0,0,0,0,0,0,0,0};
    #pragma unroll
    for (int dh = 0; dh < 3; ++dh) {
      int hh = h + dh - 1;
      if (hh < 0 || hh >= HDIM) continue;    // block-uniform branch
      #pragma unroll
      for (int dw = 0; dw < 3; ++dw) {
        int ww = wq + dw - 1;
        if (ww < 0 || ww >= WDIM) continue;  // block-uniform branch
        uint4 v  = *(const uint4*)&zx[rowbase + (long)((dh-1)*WDIM + (dw-1)) * DPROJ + c];
        uint4 wt = *(const uint4*)&keffall[(dh*3 + dw) * NCV + c];
        fma_mix_lo(acc[0], v.x, wt.x);  fma_mix_hi(acc[1], v.x, wt.x);
        fma_mix_lo(acc[2], v.y, wt.y);  fma_mix_hi(acc[3], v.y, wt.y);
        fma_mix_lo(acc[4], v.z, wt.z);  fma_mix_hi(acc[5], v.z, wt.z);
        fma_mix_lo(acc[6], v.w, wt.w);  fma_mix_hi(acc[7], v.w, wt.w);
      }
    }
    f16x8 o8;
    if (c < 1024) {
      float a2 = a2_p[0];
      #pragma unroll
      for (int j = 0; j < 8; ++j) o8[j] = (f16)(a2 * siluf(acc[j]));
      *(f16x8*)&g2[(long)l * 2048 + 1024 + c] = o8;
    } else {
      #pragma unroll
      for (int j = 0; j < 8; ++j) o8[j] = (f16)siluf(acc[j]);
      *(f16x8*)&xbc[(long)l * CONVD + (c - 1024)] = o8;
    }
  } else if (t < 280) {                      // dt -> dA, 8 heads per thread
    int hd = (t - 264) * 8;
    f16x8 x = *(const f16x8*)&zx[rowbase + NCV + hd];
    f32x4 o0, o1;
    #pragma unroll
    for (int j = 0; j < 8; ++j) {
      float xx = (float)x[j] + dt_bias[hd + j];
      float sp = (xx > 20.f) ? xx : log1pf(__expf(xx));
      float dv = sp * __expf(A_log[hd + j]);
      if (j < 4) o0[j] = dv; else o1[j-4] = dv;
    }
    *(f32x4*)&dAb[(long)l * 128 + hd]     = o0;
    *(f32x4*)&dAb[(long)l * 128 + hd + 4] = o1;
  }
}

// ---------------- KV partials over 32-token slices, then reduce ----------------
__global__ __launch_bounds__(512) void k_kv_part(const f16* __restrict__ xbc,
                                                 const float* __restrict__ dA,
                                                 float* __restrict__ part) {
  int t = threadIdx.x;
  int m = t >> 3, p = t & 7;                 // m: head-pair 0..63, p: headdim 0..7
  int lc = blockIdx.x, b = blockIdx.y;       // lc: 0..127 (32 tokens each), b chunk-local
  float acc0[16], acc1[16];
  #pragma unroll
  for (int s = 0; s < 16; ++s) { acc0[s] = 0.f; acc1[s] = 0.f; }
  long lbase = (long)b * LPB + lc * 32;
  for (int li = 0; li < 32; ++li) {
    long row = lbase + li;
    const f16* xr = xbc + row * CONVD;
    float a0 = dA[row * 128 + 2*m];
    float a1 = dA[row * 128 + 2*m + 1];
    float xv0 = (float)xr[16*m + p]     * a0;   // head 2m   (group 0)
    float xv1 = (float)xr[16*m + 8 + p] * a1;   // head 2m+1 (group 1)
    const f16* Br = xr + DIN;                   // Bm, uniform across threads
    #pragma unroll
    for (int s = 0; s < 16; ++s) {
      acc0[s] = fmaf((float)Br[s],      xv0, acc0[s]);
      acc1[s] = fmaf((float)Br[16 + s], xv1, acc1[s]);
    }
  }
  long base = ((long)(b*128 + lc)) * 16384 + (long)m * 256;
  #pragma unroll
  for (int s = 0; s < 16; ++s) {
    part[base + s*8 + p]       = acc0[s];
    part[base + 128 + s*8 + p] = acc1[s];
  }
}

__global__ __launch_bounds__(256) void k_kv_red(const float* __restrict__ part,
                                                float* __restrict__ KV) {
  int e = blockIdx.x * 256 + threadIdx.x;   // 16384 per b
  int b = blockIdx.y;
  float s = 0.f;
  #pragma unroll 4
  for (int lc = 0; lc < 128; ++lc) s += part[((long)(b*128 + lc)) * 16384 + e];
  KV[(long)b * 16384 + e] = s;
}

// --- y = Q*KV + x*Dp, LayerNorm, scale/shift, *alpha1 -> g2 cols [0,1024) f16 ---
__global__ __launch_bounds__(256) void k_y_ln(const f16* __restrict__ xbc,
                                              const float* __restrict__ KV,
                                              const float* __restrict__ Dp,
                                              const float* __restrict__ ln_g,
                                              const float* __restrict__ ln_b,
                                              const float* __restrict__ sc_p,
                                              const float* __restrict__ sh_p,
                                              const float* __restrict__ a1_p,
                                              f16* __restrict__ g2) {
  __shared__ float Qs[32][32];
  __shared__ float red[8];
  int t = threadIdx.x;
  int hd = t >> 1, pb = (t & 1) * 4;
  int m = hd >> 1, g = hd & 1;
  int b = blockIdx.x >> 7;                  // chunk-local batch (128 groups/batch)
  long l0 = (long)b * LPB + (blockIdx.x & 127) * 32;

  f32x4 kv[16];
  #pragma unroll
  for (int s = 0; s < 16; ++s)
    kv[s] = *(const f32x4*)&KV[(long)b * 16384 + m*256 + g*128 + s*8 + pb];

  for (int i = t; i < 32*32; i += 256) {
    int tok = i >> 5, q = i & 31;
    Qs[tok][q] = (float)xbc[(l0 + tok) * CONVD + 1056 + q];
  }
  int c0 = hd*8 + pb;
  f32x4 lg = *(const f32x4*)&ln_g[c0];
  f32x4 lb = *(const f32x4*)&ln_b[c0];
  float dpv = Dp[hd];
  float sc = sc_p[0], sh = sh_p[0], a1 = a1_p[0];
  int wv = t >> 6, lane = t & 63;
  __syncthreads();

  for (int tok = 0; tok < 32; ++tok) {
    long row = l0 + tok;
    f16x4 xr4 = *(const f16x4*)&xbc[row * CONVD + c0];
    f32x4 yv;
    #pragma unroll
    for (int j = 0; j < 4; ++j) yv[j] = (float)xr4[j] * dpv;
    #pragma unroll
    for (int s = 0; s < 16; ++s) {
      float qv = Qs[tok][g*16 + s];
      #pragma unroll
      for (int j = 0; j < 4; ++j) yv[j] = fmaf(qv, kv[s][j], yv[j]);
    }
    float s1 = yv[0] + yv[1] + yv[2] + yv[3];
    float s2 = yv[0]*yv[0] + yv[1]*yv[1] + yv[2]*yv[2] + yv[3]*yv[3];
    #pragma unroll
    for (int off = 1; off < 64; off <<= 1) {
      s1 += __shfl_xor(s1, off, 64);
      s2 += __shfl_xor(s2, off, 64);
    }
    if (lane == 0) { red[wv*2] = s1; red[wv*2 + 1] = s2; }
    __syncthreads();
    float S1 = red[0] + red[2] + red[4] + red[6];
    float S2 = red[1] + red[3] + red[5] + red[7];
    float mu   = S1 * (1.f/1024.f);
    float var  = S2 * (1.f/1024.f) - mu*mu;
    float rstd = rsqrtf(var + 1e-5f);
    f16x4 o4;
    #pragma unroll
    for (int j = 0; j < 4; ++j) {
      float yn = (yv[j] - mu) * rstd * lg[j] + lb[j];
      o4[j] = (f16)(a1 * (yn * sc + sh));
    }
    *(f16x4*)&g2[row * 2048 + c0] = o4;
    __syncthreads();   // protect red[] before next token
  }
}

// ---------------- host launcher ----------------
extern "C" void kernel_launch(void* const* d_in, const int* in_sizes, int n_in,
                              void* d_out, int out_size, void* d_ws, size_t ws_size,
                              hipStream_t stream) {
  const float* u       = (const float*)d_in[0];
  const float* W_in    = (const float*)d_in[3];
  const float* dt_bias = (const float*)d_in[4];
  const float* A_log   = (const float*)d_in[5];
  const float* Dp      = (const float*)d_in[6];
  const float* w33     = (const float*)d_in[7];
  const float* w13x1   = (const float*)d_in[8];
  const float* w31x1   = (const float*)d_in[9];
  const float* w13x2   = (const float*)d_in[10];
  const float* w31x2   = (const float*)d_in[11];
  const float* w13bc1  = (const float*)d_in[12];
  const float* w31bc1  = (const float*)d_in[13];
  const float* w13bc2  = (const float*)d_in[14];
  const float* w31bc2  = (const float*)d_in[15];
  const float* wz      = (const float*)d_in[16];
  const float* ln_g    = (const float*)d_in[17];
  const float* ln_b    = (const float*)d_in[18];
  const float* sc      = (const float*)d_in[19];
  const float* sh      = (const float*)d_in[20];
  const float* a1      = (const float*)d_in[21];
  const float* a2      = (const float*)d_in[22];
  const float* W_out   = (const float*)d_in[23];

  // per-batch buffer bytes (u_f16 aliases g2; kv partials + gemm2 partials live in zx)
  const size_t B_G2   = 16777216;   // 4096x2048 f16
  const size_t B_ZX   = 18350080;   // 4096x2240 f16 (dead after conv; reused as partial arenas)
  const size_t B_XBC  = 8912896;    // 4096x1088 f16
  const size_t B_DA   = 2097152;    // 4096x128 f32
  const size_t B_KV   = 65536;      // 16384 f32
  const size_t perC   = B_G2 + B_ZX + B_XBC + B_DA + B_KV;   // 46.2 MB
  const size_t persist = 2359296 + 2097152 + 38912;

  int C = 8;
  while (C > 1 && persist + (size_t)C * perC > ws_size) C >>= 1;
  const int nch = 8 / C;
  const int Mc  = C * LPB;

  char* p = (char*)d_ws;
  f16*   win_f   = (f16*)p;   p += 2359296;   // 2304x512
  f16*   wout_f  = (f16*)p;   p += 2097152;   // 512x2048
  f16*   keffall = (f16*)p;   p += 38912;     // 9x2112 f16 (padded)
  char*  arena   = p;                          // u_f16 aliases g2
  f16*   g2      = (f16*)arena;
  f16*   u_f     = (f16*)arena;
  p = arena + (size_t)C * B_G2;
  f16*   zx      = (f16*)p;   p += (size_t)C * B_ZX;
  f16*   xbc     = (f16*)p;   p += (size_t)C * B_XBC;
  float* dAb     = (float*)p; p += (size_t)C * B_DA;
  float* KV      = (float*)p; p += (size_t)C * B_KV;
  // zx arena reuse after conv: kv partials (C*128*16384 f32 = C*8.4MB <= C*18.35MB),
  // then GEMM2 split-K partials (2 * Mc*512 f32 = Mc*4096B <= Mc*4480B).
  float* part  = (float*)zx;
  float* kpart = (float*)zx;

  k_cvt_win<<<4608, 256, 0, stream>>>(W_in, win_f);
  k_cvt    <<<1024, 256, 0, stream>>>(W_out, wout_f);   // 512*2048/1024
  k_keff   <<<9, 256, 0, stream>>>(w33, w13x1, w31x1, w13x2, w31x2,
                                   w13bc1, w31bc1, w13bc2, w31bc2, wz, keffall);

  for (int ch = 0; ch < nch; ++ch) {
    const float* uc   = u + (size_t)ch * Mc * 512;
    float*       outc = (float*)d_out + (size_t)ch * Mc * 512;
    const int ntm = Mc / 128;

    k_cvt<<<Mc/2, 256, 0, stream>>>(uc, u_f);   // Mc*512/1024 blocks

    // GEMM1: zx(f16) = u @ W_in^T  (N padded to 2304, store-guard 2240)
    k_gemmf<f16><<<ntm*18, 256, 0, stream>>>(u_f, 512, win_f, 512,
                                             zx, DPROJ, 512, DPROJ, 18, ntm*18, 0);

    // fused f16 conv(z->g2[:,1024:]) + conv(xBC->xbc) + dA  (v_fma_mix core)
    k_conv_all<<<Mc, 320, 0, stream>>>(zx, keffall, a2, dt_bias, A_log,
                                       xbc, g2, dAb);

    // attention KV (zx arena now dead -> partials live there)
    k_kv_part <<<dim3(128, C), 512, 0, stream>>>(xbc, dAb, part);
    k_kv_red  <<<dim3(64, C), 256, 0, stream>>>(part, KV);
    k_y_ln    <<<C*128, 256, 0, stream>>>(xbc, KV, Dp, ln_g, ln_b, sc, sh, a1, g2);

    // GEMM2: split-K=2 partials in zx arena, then reduce into out
    const long cseg = (long)Mc * 512;
    k_gemmf<float><<<ntm*4*2, 256, 0, stream>>>(g2, 2048, wout_f, 2048,
                                                kpart, 512, 1024, 512, 4, ntm*4, cseg);
    k_red2<<<Mc/2, 256, 0, stream>>>(kpart, cseg, outc);
  }
}